// Round 2
// baseline (2310.838 us; speedup 1.0000x reference)
//
#include <hip/hip_runtime.h>
#include <hip/hip_bf16.h>
#include <math.h>

#define NB 32
#define NNODE 64
#define DD 128
#define NSQ 4096        // NNODE*NNODE
#define EDGES 16384
#define LAYERS 6

__device__ __forceinline__ float silu_f(float x){ return x / (1.f + __expf(-x)); }

// ---------------- time embedding: tt[b][d] = silu(silu(t*W1+b1)@W2+b2) ----------------
__global__ void k_temb(const float* __restrict__ t, const float* __restrict__ W1,
                       const float* __restrict__ b1, const float* __restrict__ W2,
                       const float* __restrict__ b2, float* __restrict__ tt){
  int b = blockIdx.x, d = threadIdx.x;              // 128 threads
  __shared__ float h[DD];
  float v = t[b]*W1[d] + b1[d];
  h[d] = silu_f(v);
  __syncthreads();
  float acc = b2[d];
  #pragma unroll 4
  for (int k=0;k<DD;k++) acc = fmaf(h[k], W2[k*DD+d], acc);
  tt[b*DD+d] = silu_f(acc);
}

// ---------------- edge-type table: only 16 distinct edge types ----------------
__global__ void k_edgeenc(const float* __restrict__ emb, const float* __restrict__ W1,
                          const float* __restrict__ b1, const float* __restrict__ W2,
                          const float* __restrict__ b2, float* __restrict__ enc){
  int et = blockIdx.x, tid = threadIdx.x;           // 256 threads
  __shared__ float e0[DD];
  __shared__ float hid[2*DD];
  if (tid < DD) e0[tid] = emb[et*DD + tid];
  __syncthreads();
  float a = b1[tid];
  for (int d2=0; d2<DD; d2++) a = fmaf(e0[d2], W1[d2*256 + tid], a);
  hid[tid] = fmaxf(a, 0.f);
  __syncthreads();
  if (tid < DD){
    float o = b2[tid];
    for (int k=0;k<256;k++) o = fmaf(hid[k], W2[k*DD + tid], o);
    enc[et*DD + tid] = o;
  }
}

// ---------------- scatter chunk's edges into X (plane layout), scaled by tt ----------------
__global__ void k_scatter(const int* __restrict__ ei, const int* __restrict__ attr,
                          const float* __restrict__ enc, const float* __restrict__ tt,
                          float* __restrict__ X, int b0){
  int e = b0*512 + blockIdx.x*2 + (threadIdx.x>>7);
  int d = threadIdx.x & 127;
  int sfull = ei[e], dfull = ei[EDGES + e];
  int g = sfull>>6, u = sfull&63, v = dfull&63;
  float val = enc[attr[e]*DD + d] * tt[g*DD + d];
  atomicAdd(X + ((size_t)((g - b0)*DD + d)<<12) + u*64 + v, val);
}

// ---------------- einsum: per (b,d) plane: X1 = A@X, X2 = X@A ----------------
// block handles 2 consecutive planes; wave-per-(plane,product); 8x8 reg tiles
__global__ __launch_bounds__(256) void k_einsum(const float* __restrict__ A, const float* __restrict__ X,
                                                float* __restrict__ X1, float* __restrict__ X2){
  __shared__ __align__(16) float As[2*NSQ];
  __shared__ __align__(16) float Xs[2*NSQ];
  int tid = threadIdx.x;
  size_t gbase = (size_t)blockIdx.x * (2*NSQ);
  const float4* gA = (const float4*)(A + gbase);
  const float4* gX = (const float4*)(X + gbase);
  float4* lA = (float4*)As; float4* lX = (float4*)Xs;
  #pragma unroll
  for (int q = 0; q < 2048; q += 256){ lA[q+tid] = gA[q+tid]; lX[q+tid] = gX[q+tid]; }
  __syncthreads();
  int dl = tid>>7, prod = (tid>>6)&1, t = tid&63, ty = t>>3, tx = t&7;
  const float* P = prod ? (Xs + dl*NSQ) : (As + dl*NSQ);
  const float* Q = prod ? (As + dl*NSQ) : (Xs + dl*NSQ);
  float acc[8][8] = {};
  for (int k4=0;k4<64;k4+=4){
    float4 av[8];
    #pragma unroll
    for (int p=0;p<8;p++) av[p] = *(const float4*)(P + (ty*8+p)*64 + k4);
    #pragma unroll
    for (int kk=0;kk<4;kk++){
      float4 b0 = *(const float4*)(Q + (k4+kk)*64 + tx*8);
      float4 b1 = *(const float4*)(Q + (k4+kk)*64 + tx*8 + 4);
      float bb[8] = {b0.x,b0.y,b0.z,b0.w,b1.x,b1.y,b1.z,b1.w};
      #pragma unroll
      for (int p=0;p<8;p++){
        float a = (kk==0)?av[p].x:(kk==1)?av[p].y:(kk==2)?av[p].z:av[p].w;
        #pragma unroll
        for (int q=0;q<8;q++) acc[p][q] = fmaf(a, bb[q], acc[p][q]);
      }
    }
  }
  float* OUT = (prod ? X2 : X1) + gbase + (size_t)dl*NSQ;
  #pragma unroll
  for (int p=0;p<8;p++){
    *(float4*)(OUT + (ty*8+p)*64 + tx*8)     = make_float4(acc[p][0],acc[p][1],acc[p][2],acc[p][3]);
    *(float4*)(OUT + (ty*8+p)*64 + tx*8 + 4) = make_float4(acc[p][4],acc[p][5],acc[p][6],acc[p][7]);
  }
}

// ---------------- transposed GEMM: out[fo][col] = act(LN?(sum_fi W[fi][fo]*cat[fi][col] + bias)) ----------------
// MODE 0: LN+relu, store          (conv layer 1)
// MODE 1: LN+relu, residual add   (conv layer 2; out==res)
// MODE 2: silu, store             (mlp hidden)
template<int KDIM, int MODE>
__global__ __launch_bounds__(256) void k_conv(const float* __restrict__ in0, const float* __restrict__ in1,
    const float* __restrict__ in2, const float* __restrict__ W, const float* __restrict__ bias,
    const float* __restrict__ gamma, const float* __restrict__ beta,
    float* __restrict__ out, const float* __restrict__ res){
  __shared__ __align__(16) float Wc[16][128];
  __shared__ __align__(16) float Cc[16][128];
  __shared__ float redS[16][128];
  __shared__ float redQ[16][128];
  __shared__ float stats[128][2];
  int tid = threadIdx.x;
  int tf = tid>>4, tc = tid&15;
  int colTile = blockIdx.x << 7;
  int b = colTile >> 12;
  int colInB = colTile & 4095;
  float acc[8][8] = {};
  for (int fi0 = 0; fi0 < KDIM; fi0 += 16){
    __syncthreads();
    int flat = tid*8; int r = flat>>7; int c = flat&127;
    {
      const float* wsrc = W + (fi0+r)*128 + c;
      *(float4*)&Wc[r][c]   = *(const float4*)wsrc;
      *(float4*)&Wc[r][c+4] = *(const float4*)(wsrc+4);
    }
    {
      int fi = fi0 + r;
      const float* T = (KDIM==128) ? in0 : ((fi<128)? in0 : (fi<256? in1 : in2));
      int d = fi & 127;
      const float* csrc = T + ((size_t)(b*128 + d)<<12) + colInB + c;
      *(float4*)&Cc[r][c]   = *(const float4*)csrc;
      *(float4*)&Cc[r][c+4] = *(const float4*)(csrc+4);
    }
    __syncthreads();
    #pragma unroll
    for (int k=0;k<16;k++){
      float4 w0 = *(const float4*)&Wc[k][tf*8];
      float4 w1 = *(const float4*)&Wc[k][tf*8+4];
      float4 c0 = *(const float4*)&Cc[k][tc*4];
      float4 c1 = *(const float4*)&Cc[k][64 + tc*4];
      float wv[8] = {w0.x,w0.y,w0.z,w0.w,w1.x,w1.y,w1.z,w1.w};
      float cv[8] = {c0.x,c0.y,c0.z,c0.w,c1.x,c1.y,c1.z,c1.w};
      #pragma unroll
      for (int p=0;p<8;p++)
        #pragma unroll
        for (int q=0;q<8;q++) acc[p][q] = fmaf(wv[p], cv[q], acc[p][q]);
    }
  }
  #pragma unroll
  for (int p=0;p<8;p++){ float bv = bias[tf*8+p];
    #pragma unroll
    for (int q=0;q<8;q++) acc[p][q] += bv; }

  if (MODE == 2){
    #pragma unroll
    for (int p=0;p<8;p++){
      int fo = tf*8+p;
      size_t rowbase = ((size_t)(b*128 + fo)<<12) + colInB;
      float o[8];
      #pragma unroll
      for (int q=0;q<8;q++) o[q] = silu_f(acc[p][q]);
      *(float4*)(out + rowbase + tc*4)      = make_float4(o[0],o[1],o[2],o[3]);
      *(float4*)(out + rowbase + 64 + tc*4) = make_float4(o[4],o[5],o[6],o[7]);
    }
  } else {
    float cs[8] = {}, cq[8] = {};
    #pragma unroll
    for (int p=0;p<8;p++)
      #pragma unroll
      for (int q=0;q<8;q++){ cs[q] += acc[p][q]; cq[q] = fmaf(acc[p][q], acc[p][q], cq[q]); }
    #pragma unroll
    for (int q=0;q<8;q++){
      int col = (q<4) ? (tc*4+q) : (64 + tc*4 + (q-4));
      redS[tf][col] = cs[q]; redQ[tf][col] = cq[q];
    }
    __syncthreads();
    if (tid < 128){
      float S=0.f, Qs=0.f;
      #pragma unroll
      for (int r2=0;r2<16;r2++){ S += redS[r2][tid]; Qs += redQ[r2][tid]; }
      float m = S*(1.f/128.f);
      float var = Qs*(1.f/128.f) - m*m;
      stats[tid][0] = m; stats[tid][1] = rsqrtf(var + 1e-5f);
    }
    __syncthreads();
    #pragma unroll
    for (int p=0;p<8;p++){
      int fo = tf*8+p;
      float ga = gamma[fo], be = beta[fo];
      size_t rowbase = ((size_t)(b*128 + fo)<<12) + colInB;
      float o[8];
      #pragma unroll
      for (int q=0;q<8;q++){
        int col = (q<4) ? (tc*4+q) : (64 + tc*4 + (q-4));
        float xx = (acc[p][q] - stats[col][0]) * stats[col][1] * ga + be;
        o[q] = fmaxf(xx, 0.f);
      }
      if (MODE == 1){
        float4 r0 = *(const float4*)(res + rowbase + tc*4);
        float4 r1 = *(const float4*)(res + rowbase + 64 + tc*4);
        o[0]+=r0.x; o[1]+=r0.y; o[2]+=r0.z; o[3]+=r0.w;
        o[4]+=r1.x; o[5]+=r1.y; o[6]+=r1.z; o[7]+=r1.w;
      }
      *(float4*)(out + rowbase + tc*4)      = make_float4(o[0],o[1],o[2],o[3]);
      *(float4*)(out + rowbase + 64 + tc*4) = make_float4(o[4],o[5],o[6],o[7]);
    }
  }
}

// ---------------- z = hid@W2 + b2, then mean over j -> h2[(b,i)][fo] ----------------
__global__ __launch_bounds__(256) void k_zmean(const float* __restrict__ in0, const float* __restrict__ W,
    const float* __restrict__ bias, float* __restrict__ h2){
  __shared__ __align__(16) float Wc[16][128];
  __shared__ __align__(16) float Cc[16][128];
  __shared__ float redh[128][33];
  int tid = threadIdx.x, tf = tid>>4, tc = tid&15;
  int colTile = blockIdx.x << 7;
  int b = colTile >> 12;
  int colInB = colTile & 4095;
  float acc[8][8] = {};
  for (int fi0 = 0; fi0 < 128; fi0 += 16){
    __syncthreads();
    int flat = tid*8; int r = flat>>7; int c = flat&127;
    *(float4*)&Wc[r][c]   = *(const float4*)(W + (fi0+r)*128 + c);
    *(float4*)&Wc[r][c+4] = *(const float4*)(W + (fi0+r)*128 + c + 4);
    const float* csrc = in0 + ((size_t)(b*128 + fi0 + r)<<12) + colInB + c;
    *(float4*)&Cc[r][c]   = *(const float4*)csrc;
    *(float4*)&Cc[r][c+4] = *(const float4*)(csrc+4);
    __syncthreads();
    #pragma unroll
    for (int k=0;k<16;k++){
      float4 w0 = *(const float4*)&Wc[k][tf*8];
      float4 w1 = *(const float4*)&Wc[k][tf*8+4];
      float4 c0 = *(const float4*)&Cc[k][tc*4];
      float4 c1 = *(const float4*)&Cc[k][64 + tc*4];
      float wv[8] = {w0.x,w0.y,w0.z,w0.w,w1.x,w1.y,w1.z,w1.w};
      float cv[8] = {c0.x,c0.y,c0.z,c0.w,c1.x,c1.y,c1.z,c1.w};
      #pragma unroll
      for (int p=0;p<8;p++)
        #pragma unroll
        for (int q=0;q<8;q++) acc[p][q] = fmaf(wv[p], cv[q], acc[p][q]);
    }
  }
  #pragma unroll
  for (int p=0;p<8;p++){
    float sA=0.f, sB=0.f;
    #pragma unroll
    for (int q=0;q<4;q++) sA += acc[p][q];
    #pragma unroll
    for (int q=4;q<8;q++) sB += acc[p][q];
    redh[tf*8+p][tc*2+0] = sA;
    redh[tf*8+p][tc*2+1] = sB;
  }
  __syncthreads();
  int fo = tid>>1, il = tid&1;
  float S=0.f;
  #pragma unroll
  for (int c2=0;c2<16;c2++) S += redh[fo][c2*2+il];
  int i0 = colInB>>6;
  h2[(size_t)(b*64 + i0 + il)*128 + fo] = S*(1.f/64.f) + bias[fo];
}

// ---------------- X = X + X^T per plane (in-place via LDS staging) ----------------
__global__ __launch_bounds__(256) void k_sym(float* __restrict__ X){
  __shared__ float P[NNODE][NNODE+1];
  size_t base = (size_t)blockIdx.x * NSQ;
  int tid = threadIdx.x;
  for (int s=0;s<NSQ;s+=256){ int idx = s + tid; P[idx>>6][idx&63] = X[base+idx]; }
  __syncthreads();
  for (int s=0;s<NSQ;s+=256){ int idx = s + tid; int i = idx>>6, j = idx&63;
    X[base+idx] = P[i][j] + P[j][i]; }
}

// ---------------- final MLP for edges: gather X[g,:,u,v] -> fn MLP ----------------
__global__ __launch_bounds__(256) void k_fedge(const float* __restrict__ X, const int* __restrict__ ei,
    const float* __restrict__ W1, const float* __restrict__ b1,
    const float* __restrict__ W2, const float* __restrict__ b2, float* __restrict__ outp, int b0){
  __shared__ float eo[16][128];
  __shared__ float hid[16][256];
  int tid = threadIdx.x;
  int e0 = b0*512 + blockIdx.x*16;
  for (int s=0;s<8;s++){
    int flat = tid + s*256; int el = flat>>7; int d = flat&127;
    int e = e0 + el;
    int sfull = ei[e], dfull = ei[EDGES + e];
    int g = (sfull>>6) - b0, u = sfull&63, v = dfull&63;
    eo[el][d] = X[((size_t)(g*DD + d)<<12) + u*64 + v];
  }
  __syncthreads();
  float h[16];
  { float bb = b1[tid];
    #pragma unroll
    for (int e2=0;e2<16;e2++) h[e2] = bb; }
  for (int d2=0; d2<128; d2++){
    float w = W1[d2*256 + tid];
    #pragma unroll
    for (int e2=0;e2<16;e2++) h[e2] = fmaf(eo[e2][d2], w, h[e2]);
  }
  #pragma unroll
  for (int e2=0;e2<16;e2++) hid[e2][tid] = fmaxf(h[e2], 0.f);
  __syncthreads();
  int dd2 = tid & 127, half = tid >> 7;
  float o[8];
  { float bo = b2[dd2];
    #pragma unroll
    for (int i=0;i<8;i++) o[i] = bo; }
  for (int k=0;k<256;k++){
    float w = W2[k*128 + dd2];
    #pragma unroll
    for (int i=0;i<8;i++) o[i] = fmaf(hid[half*8+i][k], w, o[i]);
  }
  #pragma unroll
  for (int i=0;i<8;i++) outp[(size_t)(e0 + half*8 + i)*128 + dd2] = o[i];
}

// ---------------- final MLP for nodes: rows from h2 ----------------
__global__ __launch_bounds__(256) void k_fnode(const float* __restrict__ h2,
    const float* __restrict__ W1, const float* __restrict__ b1,
    const float* __restrict__ W2, const float* __restrict__ b2, float* __restrict__ outp){
  __shared__ float eo[16][128];
  __shared__ float hid[16][256];
  int tid = threadIdx.x;
  int r0 = blockIdx.x*16;
  for (int s=0;s<8;s++){
    int flat = tid + s*256; int el = flat>>7; int d = flat&127;
    eo[el][d] = h2[(size_t)(r0+el)*128 + d];
  }
  __syncthreads();
  float h[16];
  { float bb = b1[tid];
    #pragma unroll
    for (int e2=0;e2<16;e2++) h[e2] = bb; }
  for (int d2=0; d2<128; d2++){
    float w = W1[d2*256 + tid];
    #pragma unroll
    for (int e2=0;e2<16;e2++) h[e2] = fmaf(eo[e2][d2], w, h[e2]);
  }
  #pragma unroll
  for (int e2=0;e2<16;e2++) hid[e2][tid] = fmaxf(h[e2], 0.f);
  __syncthreads();
  int dd2 = tid & 127, half = tid >> 7;
  float o[8];
  { float bo = b2[dd2];
    #pragma unroll
    for (int i=0;i<8;i++) o[i] = bo; }
  for (int k=0;k<256;k++){
    float w = W2[k*128 + dd2];
    #pragma unroll
    for (int i=0;i<8;i++) o[i] = fmaf(hid[half*8+i][k], w, o[i]);
  }
  #pragma unroll
  for (int i=0;i<8;i++) outp[(size_t)(r0 + half*8 + i)*128 + dd2] = o[i];
}

// ---------------- graph_attr = mean over nodes ----------------
__global__ void k_graph(const float* __restrict__ node_out, float* __restrict__ gout){
  int b = blockIdx.x, d = threadIdx.x;   // 128 threads
  float s = 0.f;
  for (int i=0;i<64;i++) s += node_out[(size_t)(b*64+i)*128 + d];
  gout[b*128 + d] = s * (1.f/64.f);
}

extern "C" void kernel_launch(void* const* d_in, const int* in_sizes, int n_in,
                              void* d_out, int out_size, void* d_ws, size_t ws_size,
                              hipStream_t stream) {
  const int*   edge_index = (const int*)d_in[1];
  const int*   edge_attr  = (const int*)d_in[2];
  const float* t        = (const float*)d_in[3];
  const float* edge_emb = (const float*)d_in[5];
  const float* temb_W1  = (const float*)d_in[6];
  const float* temb_b1  = (const float*)d_in[7];
  const float* temb_W2  = (const float*)d_in[8];
  const float* temb_b2  = (const float*)d_in[9];
  const float* ein_W1   = (const float*)d_in[14];
  const float* ein_b1   = (const float*)d_in[15];
  const float* ein_W2   = (const float*)d_in[16];
  const float* ein_b2   = (const float*)d_in[17];
  const float* conv_W1  = (const float*)d_in[18];
  const float* conv_b1  = (const float*)d_in[19];
  const float* conv_g1  = (const float*)d_in[20];
  const float* conv_bt1 = (const float*)d_in[21];
  const float* conv_W2  = (const float*)d_in[22];
  const float* conv_b2  = (const float*)d_in[23];
  const float* conv_g2  = (const float*)d_in[24];
  const float* conv_bt2 = (const float*)d_in[25];
  const float* mlp_W1   = (const float*)d_in[26];
  const float* mlp_b1   = (const float*)d_in[27];
  const float* mlp_W2   = (const float*)d_in[28];
  const float* mlp_b2   = (const float*)d_in[29];
  const float* fn_W1    = (const float*)d_in[30];
  const float* fn_b1    = (const float*)d_in[31];
  const float* fn_W2    = (const float*)d_in[32];
  const float* fn_b2    = (const float*)d_in[33];

  float* ws  = (float*)d_ws;
  float* tt  = ws;            // 4096 f32
  float* enc = ws + 4096;     // 2048 f32
  float* h2  = ws + 6144;     // up to 262144 f32 (C*64*128)
  const size_t HDR = 524288;  // floats reserved for the small buffers

  // pick the largest batch-chunk C whose 4 plane buffers fit in d_ws
  size_t availF = ws_size / sizeof(float);
  const int cands[5] = {16, 8, 4, 2, 1};
  int C = 1;
  for (int i = 0; i < 5; i++){
    if (HDR + 4ull * (size_t)cands[i] * 524288ull <= availF){ C = cands[i]; break; }
  }
  const size_t PC = (size_t)C * 524288;   // floats per plane buffer (C*128*4096)
  float* Ap  = ws + HDR;
  float* Xp  = Ap + PC;
  float* X1p = Xp + PC;
  float* X2p = X1p + PC;
  float* outf = (float*)d_out;

  k_temb<<<NB, DD, 0, stream>>>(t, temb_W1, temb_b1, temb_W2, temb_b2, tt);
  k_edgeenc<<<16, 256, 0, stream>>>(edge_emb, ein_W1, ein_b1, ein_W2, ein_b2, enc);

  for (int b0 = 0; b0 < NB; b0 += C){
    hipMemsetAsync(Xp, 0, PC*sizeof(float), stream);
    k_scatter<<<C*256, 256, 0, stream>>>(edge_index, edge_attr, enc, tt, Xp, b0);
    hipMemcpyAsync(Ap, Xp, PC*sizeof(float), hipMemcpyDeviceToDevice, stream);

    for (int l=0; l<LAYERS; l++){
      k_einsum<<<C*64, 256, 0, stream>>>(Ap, Xp, X1p, X2p);
      k_conv<384,0><<<C*32, 256, 0, stream>>>(Xp, X1p, X2p, conv_W1 + (size_t)l*384*DD, conv_b1 + l*DD,
                                              conv_g1 + l*DD, conv_bt1 + l*DD, X1p, nullptr);
      k_conv<128,1><<<C*32, 256, 0, stream>>>(X1p, nullptr, nullptr, conv_W2 + (size_t)l*DD*DD, conv_b2 + l*DD,
                                              conv_g2 + l*DD, conv_bt2 + l*DD, Xp, Xp);
    }

    k_sym<<<C*128, 256, 0, stream>>>(Xp);
    k_conv<128,2><<<C*32, 256, 0, stream>>>(Xp, nullptr, nullptr, mlp_W1, mlp_b1, nullptr, nullptr, X1p, nullptr);
    k_zmean<<<C*32, 256, 0, stream>>>(X1p, mlp_W2, mlp_b2, h2);
    k_fedge<<<C*32, 256, 0, stream>>>(Xp, edge_index, fn_W1, fn_b1, fn_W2, fn_b2, outf + 262144, b0);
    k_fnode<<<C*4, 256, 0, stream>>>(h2, fn_W1, fn_b1, fn_W2, fn_b2, outf + (size_t)b0*64*DD);
    k_graph<<<C, DD, 0, stream>>>(outf + (size_t)b0*64*DD, outf + 2359296 + b0*DD);
  }
}

// Round 3
// 1351.862 us; speedup vs baseline: 1.7094x; 1.7094x over previous
//
#include <hip/hip_runtime.h>
#include <hip/hip_bf16.h>
#include <math.h>

#define NB 32
#define NNODE 64
#define DD 128
#define NSQ 4096
#define EDGES 16384
#define LAYERS 6

typedef __bf16 bf16x8 __attribute__((ext_vector_type(8)));
typedef float f32x4 __attribute__((ext_vector_type(4)));

__device__ __forceinline__ float silu_f(float x){ return x / (1.f + __expf(-x)); }

// ---------------- time embedding ----------------
__global__ void k_temb(const float* __restrict__ t, const float* __restrict__ W1,
                       const float* __restrict__ b1, const float* __restrict__ W2,
                       const float* __restrict__ b2, float* __restrict__ tt){
  int b = blockIdx.x, d = threadIdx.x;
  __shared__ float h[DD];
  float v = t[b]*W1[d] + b1[d];
  h[d] = silu_f(v);
  __syncthreads();
  float acc = b2[d];
  #pragma unroll 4
  for (int k=0;k<DD;k++) acc = fmaf(h[k], W2[k*DD+d], acc);
  tt[b*DD+d] = silu_f(acc);
}

// ---------------- edge-type table ----------------
__global__ void k_edgeenc(const float* __restrict__ emb, const float* __restrict__ W1,
                          const float* __restrict__ b1, const float* __restrict__ W2,
                          const float* __restrict__ b2, float* __restrict__ enc){
  int et = blockIdx.x, tid = threadIdx.x;
  __shared__ float e0[DD];
  __shared__ float hid[2*DD];
  if (tid < DD) e0[tid] = emb[et*DD + tid];
  __syncthreads();
  float a = b1[tid];
  for (int d2=0; d2<DD; d2++) a = fmaf(e0[d2], W1[d2*256 + tid], a);
  hid[tid] = fmaxf(a, 0.f);
  __syncthreads();
  if (tid < DD){
    float o = b2[tid];
    for (int k=0;k<256;k++) o = fmaf(hid[k], W2[k*DD + tid], o);
    enc[et*DD + tid] = o;
  }
}

// ---------------- scatter into S-layout planes (elem v*64+u), scaled by tt ----------------
__global__ void k_scatter(const int* __restrict__ ei, const int* __restrict__ attr,
                          const float* __restrict__ enc, const float* __restrict__ tt,
                          float* __restrict__ X, int b0){
  int e = b0*512 + blockIdx.x*2 + (threadIdx.x>>7);
  int d = threadIdx.x & 127;
  int sfull = ei[e], dfull = ei[EDGES + e];
  int g = sfull>>6, u = sfull&63, v = dfull&63;
  float val = enc[attr[e]*DD + d] * tt[g*DD + d];
  atomicAdd(X + ((size_t)((g - b0)*DD + d)<<12) + v*64 + u, val);
}

// ---------------- prep: Xp(f32 S) -> At (bf16 copy of S) + An (bf16 transpose) ----------------
__global__ __launch_bounds__(256) void k_prep(const float* __restrict__ Xp,
                                              __bf16* __restrict__ At, __bf16* __restrict__ An){
  __shared__ float L[64][65];
  size_t base = (size_t)blockIdx.x * 4096;
  int t = threadIdx.x;
  int f = t*16, r = f>>6, c = f&63;
  float v[16];
  #pragma unroll
  for (int e=0;e<4;e++){
    float4 x = *(const float4*)(Xp + base + f + e*4);
    v[e*4+0]=x.x; v[e*4+1]=x.y; v[e*4+2]=x.z; v[e*4+3]=x.w;
  }
  union { __bf16 h[16]; uint4 u[2]; } pk;
  #pragma unroll
  for (int e=0;e<16;e++){ L[r][c+e] = v[e]; pk.h[e] = (__bf16)v[e]; }
  *(uint4*)(At + base + f)     = pk.u[0];
  *(uint4*)(At + base + f + 8) = pk.u[1];
  __syncthreads();
  union { __bf16 h[16]; uint4 u[2]; } pk2;
  #pragma unroll
  for (int e=0;e<16;e++) pk2.h[e] = (__bf16)L[c+e][r];
  *(uint4*)(An + base + f)     = pk2.u[0];
  *(uint4*)(An + base + f + 8) = pk2.u[1];
}

// ---------------- bf16 plane transpose: Xt(S) -> Xn (normal) ----------------
__global__ __launch_bounds__(256) void k_transpose(const __bf16* __restrict__ src, __bf16* __restrict__ dst){
  __shared__ unsigned short L[64][65];
  size_t base = (size_t)blockIdx.x * 4096;
  int t = threadIdx.x;
  int f = t*16, r = f>>6, c = f&63;
  union { unsigned short h[16]; uint4 u[2]; } in;
  in.u[0] = *(const uint4*)((const unsigned short*)src + base + f);
  in.u[1] = *(const uint4*)((const unsigned short*)src + base + f + 8);
  #pragma unroll
  for (int e=0;e<16;e++) L[r][c+e] = in.h[e];
  __syncthreads();
  union { unsigned short h[16]; uint4 u[2]; } o;
  #pragma unroll
  for (int e=0;e<16;e++) o.h[e] = L[c+e][r];
  *(uint4*)((unsigned short*)dst + base + f)     = o.u[0];
  *(uint4*)((unsigned short*)dst + base + f + 8) = o.u[1];
}

// ---------------- weight prep: transpose+convert to bf16 Wt[fo][K] ----------------
__global__ __launch_bounds__(256) void k_wprep(const float* __restrict__ W1, const float* __restrict__ W2,
                                               const float* __restrict__ Wm, __bf16* __restrict__ WT){
  int b = blockIdx.x, t = threadIdx.x;
  const float* src; __bf16* dst; int K;
  if (b < 6){ src = W1 + (size_t)b*384*128; dst = WT + (size_t)b*49152; K = 384; }
  else if (b < 12){ src = W2 + (size_t)(b-6)*128*128; dst = WT + 294912 + (size_t)(b-6)*16384; K = 128; }
  else { src = Wm; dst = WT + 393216; K = 128; }
  __shared__ float L[64][129];
  for (int k0 = 0; k0 < K; k0 += 64){
    __syncthreads();
    int r = t>>2, c = (t&3)*32;
    #pragma unroll
    for (int e=0;e<32;e+=4){
      float4 x = *(const float4*)(src + (size_t)(k0+r)*128 + c + e);
      L[r][c+e]=x.x; L[r][c+e+1]=x.y; L[r][c+e+2]=x.z; L[r][c+e+3]=x.w;
    }
    __syncthreads();
    int fo = t>>1, kk = (t&1)*32;
    union { __bf16 h[32]; uint4 u[4]; } o;
    #pragma unroll
    for (int e=0;e<32;e++) o.h[e] = (__bf16)L[kk+e][fo];
    uint4* d4 = (uint4*)(dst + (size_t)fo*K + k0 + kk);
    d4[0]=o.u[0]; d4[1]=o.u[1]; d4[2]=o.u[2]; d4[3]=o.u[3];
  }
}

// ---------------- einsum (MFMA): X1 = A@X (An,Xt), X2 = X@A (Xn,At); outputs stored transposed ----------------
__global__ __launch_bounds__(256) void k_einsum(const __bf16* __restrict__ An, const __bf16* __restrict__ At,
                                                const __bf16* __restrict__ Xn, const __bf16* __restrict__ Xt,
                                                __bf16* __restrict__ X1t, __bf16* __restrict__ X2t){
  __shared__ __bf16 S[8][4096];
  int tid = threadIdx.x;
  size_t p0 = (size_t)blockIdx.x * 2;
  const __bf16* srcs[4] = {An, At, Xn, Xt};
  #pragma unroll
  for (int bI = 0; bI < 8; bI++){
    const uint4* g = (const uint4*)(srcs[bI>>1] + (p0 + (bI&1))*4096);
    #pragma unroll
    for (int s = 0; s < 2; s++){
      int idx = tid + s*256;
      uint4 v = g[idx];
      int row = idx>>3; int slot = idx&7;
      *(uint4*)&S[bI][row*64 + ((slot ^ (row&7))<<3)] = v;
    }
  }
  __syncthreads();
  int w = tid>>6, lane = tid&63;
  int pl = w>>1, pr = w&1;
  const __bf16* M  = pr ? S[4+pl] : S[0+pl];
  const __bf16* Bt = pr ? S[2+pl] : S[6+pl];
  f32x4 acc[4][4];
  #pragma unroll
  for (int a=0;a<4;a++)
    #pragma unroll
    for(int b=0;b<4;b++) acc[a][b] = (f32x4){0.f,0.f,0.f,0.f};
  int lr = lane&15, lq = lane>>4;
  #pragma unroll
  for (int ks=0;ks<2;ks++){
    bf16x8 af[4], bfr[4];
    #pragma unroll
    for (int mt=0;mt<4;mt++){ int r = mt*16+lr; af[mt] = *(const bf16x8*)&M[r*64 + (((ks*4+lq) ^ (r&7))<<3)]; }
    #pragma unroll
    for (int nt=0;nt<4;nt++){ int r = nt*16+lr; bfr[nt] = *(const bf16x8*)&Bt[r*64 + (((ks*4+lq) ^ (r&7))<<3)]; }
    #pragma unroll
    for (int mt=0;mt<4;mt++)
      #pragma unroll
      for (int nt=0;nt<4;nt++)
        acc[mt][nt] = __builtin_amdgcn_mfma_f32_16x16x32_bf16(af[mt], bfr[nt], acc[mt][nt], 0,0,0);
  }
  __bf16* OUT = (pr ? X2t : X1t) + (p0+pl)*4096;
  #pragma unroll
  for (int mt=0;mt<4;mt++)
    #pragma unroll
    for (int nt=0;nt<4;nt++){
      int col = nt*16 + lr; int row0 = mt*16 + lq*4;
      union { __bf16 h[4]; uint2 u; } o;
      #pragma unroll
      for (int r=0;r<4;r++) o.h[r] = (__bf16)acc[mt][nt][r];
      *(uint2*)&OUT[col*64 + row0] = o.u;   // store D[row][col] at transposed pos
    }
}

// ---------------- conv (MFMA, fused LN): D[fo][col] = Wt . cat^T ----------------
// MODE 0: LN+relu -> outb          MODE 1: LN+relu + res -> outb(bf16) + resio(f32)   MODE 2: silu -> outb
template<int KDIM, int MODE>
__global__ __launch_bounds__(256) void k_convm(const __bf16* __restrict__ in0, const __bf16* __restrict__ in1,
    const __bf16* __restrict__ in2, const __bf16* __restrict__ Wt, const float* __restrict__ bias,
    const float* __restrict__ gamma, const float* __restrict__ beta,
    __bf16* __restrict__ outb, float* __restrict__ resio){
  __shared__ __bf16 Wc[128*32];
  __shared__ __bf16 Cc[128*32];
  __shared__ float redS[4][128], redQ[4][128];
  __shared__ float stats[2][128];
  int tid = threadIdx.x, w = tid>>6, lane = tid&63, lr = lane&15, lq = lane>>4;
  int colTile = blockIdx.x << 7;
  int bl = colTile >> 12;
  int colInB = colTile & 4095;
  f32x4 acc[2][8];
  #pragma unroll
  for (int a=0;a<2;a++)
    #pragma unroll
    for (int b=0;b<8;b++) acc[a][b] = (f32x4){0.f,0.f,0.f,0.f};

  for (int ks=0; ks<KDIM/32; ks++){
    __syncthreads();
    { // stage Wt slice [128 fo][32 k]
      int fo = tid>>1, half = tid&1;
      const uint4* src = (const uint4*)(Wt + (size_t)fo*KDIM + ks*32 + half*16);
      uint4 v0 = src[0], v1 = src[1];
      *(uint4*)&Wc[fo*32 + ((((half*2+0) ^ (fo&3)))<<3)] = v0;
      *(uint4*)&Wc[fo*32 + ((((half*2+1) ^ (fo&3)))<<3)] = v1;
    }
    { // stage catT slice [128 col][32 fi]  (scatter transpose)
      int fr = tid>>3; int seg = tid&7;
      int fi = ks*32 + fr;
      const __bf16* T = (KDIM==128) ? in0 : ((fi<128)? in0 : (fi<256? in1 : in2));
      int d = fi & 127;
      const __bf16* src = T + ((size_t)(bl*128 + d)<<12) + colInB + seg*16;
      union { __bf16 h[16]; uint4 u[2]; } v;
      v.u[0] = *(const uint4*)src;
      v.u[1] = *(const uint4*)(src + 8);
      #pragma unroll
      for (int e=0;e<16;e++){
        int col = seg*16 + e;
        Cc[col*32 + (fr ^ ((col&3)<<3))] = v.h[e];
      }
    }
    __syncthreads();
    bf16x8 af[2], bfr[8];
    #pragma unroll
    for (int mt=0;mt<2;mt++){ int fo = w*32 + mt*16 + lr; af[mt] = *(const bf16x8*)&Wc[fo*32 + ((lq ^ (fo&3))<<3)]; }
    #pragma unroll
    for (int nt=0;nt<8;nt++){ int cr = nt*16 + lr; bfr[nt] = *(const bf16x8*)&Cc[cr*32 + ((lq ^ (cr&3))<<3)]; }
    #pragma unroll
    for (int mt=0;mt<2;mt++)
      #pragma unroll
      for (int nt=0;nt<8;nt++)
        acc[mt][nt] = __builtin_amdgcn_mfma_f32_16x16x32_bf16(af[mt], bfr[nt], acc[mt][nt], 0,0,0);
  }

  // bias
  float bv[2][4];
  #pragma unroll
  for (int mt=0;mt<2;mt++)
    #pragma unroll
    for (int r=0;r<4;r++) bv[mt][r] = bias[w*32 + mt*16 + lq*4 + r];
  #pragma unroll
  for (int mt=0;mt<2;mt++)
    #pragma unroll
    for (int nt=0;nt<8;nt++)
      #pragma unroll
      for (int r=0;r<4;r++) acc[mt][nt][r] += bv[mt][r];

  if (MODE == 2){
    #pragma unroll
    for (int mt=0;mt<2;mt++)
      #pragma unroll
      for (int r=0;r<4;r++){
        int fo = w*32 + mt*16 + lq*4 + r;
        size_t rowb = ((size_t)(bl*128 + fo)<<12) + colInB;
        #pragma unroll
        for (int nt=0;nt<8;nt++){
          int col = nt*16 + lr;
          outb[rowb + col] = (__bf16)silu_f(acc[mt][nt][r]);
        }
      }
  } else {
    float cs[8], cq[8];
    #pragma unroll
    for (int nt=0;nt<8;nt++){ cs[nt]=0.f; cq[nt]=0.f; }
    #pragma unroll
    for (int mt=0;mt<2;mt++)
      #pragma unroll
      for (int nt=0;nt<8;nt++)
        #pragma unroll
        for (int r=0;r<4;r++){ float v = acc[mt][nt][r]; cs[nt] += v; cq[nt] = fmaf(v,v,cq[nt]); }
    #pragma unroll
    for (int nt=0;nt<8;nt++){
      cs[nt] += __shfl_xor(cs[nt], 16); cq[nt] += __shfl_xor(cq[nt], 16);
      cs[nt] += __shfl_xor(cs[nt], 32); cq[nt] += __shfl_xor(cq[nt], 32);
    }
    if (lq == 0){
      #pragma unroll
      for (int nt=0;nt<8;nt++){ redS[w][nt*16+lr] = cs[nt]; redQ[w][nt*16+lr] = cq[nt]; }
    }
    __syncthreads();
    if (tid < 128){
      float S = redS[0][tid]+redS[1][tid]+redS[2][tid]+redS[3][tid];
      float Q = redQ[0][tid]+redQ[1][tid]+redQ[2][tid]+redQ[3][tid];
      float m = S*(1.f/128.f);
      float var = Q*(1.f/128.f) - m*m;
      stats[0][tid] = m; stats[1][tid] = rsqrtf(var + 1e-5f);
    }
    __syncthreads();
    #pragma unroll
    for (int mt=0;mt<2;mt++)
      #pragma unroll
      for (int r=0;r<4;r++){
        int fo = w*32 + mt*16 + lq*4 + r;
        float ga = gamma[fo], be = beta[fo];
        size_t rowb = ((size_t)(bl*128 + fo)<<12) + colInB;
        #pragma unroll
        for (int nt=0;nt<8;nt++){
          int col = nt*16 + lr;
          float xx = (acc[mt][nt][r] - stats[0][col]) * stats[1][col] * ga + be;
          float o = fmaxf(xx, 0.f);
          if (MODE == 1){
            float nv = o + resio[rowb + col];
            resio[rowb + col] = nv;
            outb[rowb + col] = (__bf16)nv;
          } else {
            outb[rowb + col] = (__bf16)o;
          }
        }
      }
  }
}

// ---------------- X = X + X^T (f32, layout-agnostic), also emit bf16 ----------------
__global__ __launch_bounds__(256) void k_sym(float* __restrict__ X, __bf16* __restrict__ Xb){
  __shared__ float P[NNODE][NNODE+1];
  size_t base = (size_t)blockIdx.x * NSQ;
  int tid = threadIdx.x;
  for (int s=0;s<NSQ;s+=256){ int idx = s + tid; P[idx>>6][idx&63] = X[base+idx]; }
  __syncthreads();
  for (int s=0;s<NSQ;s+=256){
    int idx = s + tid; int i = idx>>6, j = idx&63;
    float v = P[i][j] + P[j][i];
    X[base+idx] = v;
    Xb[base+idx] = (__bf16)v;
  }
}

// ---------------- mean over j of S-layout planes: ym[(b,i)][d] ----------------
__global__ __launch_bounds__(256) void k_ymean(const __bf16* __restrict__ Y, float* __restrict__ ym){
  int tid = threadIdx.x; int w = tid>>6, lane = tid&63;
  int p = blockIdx.x*4 + w;
  const __bf16* pl = Y + (size_t)p*4096;
  float s = 0.f;
  for (int j=0;j<64;j++) s += (float)pl[j*64 + lane];
  int bl = p>>7, d = p&127;
  ym[(size_t)(bl*64 + lane)*128 + d] = s*(1.f/64.f);
}

// ---------------- h2 = ym @ mlp_W2 + b2 ----------------
__global__ void k_h2(const float* __restrict__ ym, const float* __restrict__ W2,
                     const float* __restrict__ b2, float* __restrict__ h2){
  int row = blockIdx.x, fo = threadIdx.x;
  __shared__ float rr[128];
  rr[fo] = ym[(size_t)row*128 + fo];
  __syncthreads();
  float a = b2[fo];
  #pragma unroll 4
  for (int k=0;k<128;k++) a = fmaf(rr[k], W2[k*128+fo], a);
  h2[(size_t)row*128+fo] = a;
}

// ---------------- final MLP for edges (gather from S-layout: v*64+u) ----------------
__global__ __launch_bounds__(256) void k_fedge(const float* __restrict__ X, const int* __restrict__ ei,
    const float* __restrict__ W1, const float* __restrict__ b1,
    const float* __restrict__ W2, const float* __restrict__ b2, float* __restrict__ outp, int b0){
  __shared__ float eo[16][128];
  __shared__ float hid[16][256];
  int tid = threadIdx.x;
  int e0 = b0*512 + blockIdx.x*16;
  for (int s=0;s<8;s++){
    int flat = tid + s*256; int el = flat>>7; int d = flat&127;
    int e = e0 + el;
    int sfull = ei[e], dfull = ei[EDGES + e];
    int g = (sfull>>6) - b0, u = sfull&63, v = dfull&63;
    eo[el][d] = X[((size_t)(g*DD + d)<<12) + v*64 + u];
  }
  __syncthreads();
  float h[16];
  { float bb = b1[tid];
    #pragma unroll
    for (int e2=0;e2<16;e2++) h[e2] = bb; }
  for (int d2=0; d2<128; d2++){
    float wv = W1[d2*256 + tid];
    #pragma unroll
    for (int e2=0;e2<16;e2++) h[e2] = fmaf(eo[e2][d2], wv, h[e2]);
  }
  #pragma unroll
  for (int e2=0;e2<16;e2++) hid[e2][tid] = fmaxf(h[e2], 0.f);
  __syncthreads();
  int dd2 = tid & 127, half = tid >> 7;
  float o[8];
  { float bo = b2[dd2];
    #pragma unroll
    for (int i=0;i<8;i++) o[i] = bo; }
  for (int k=0;k<256;k++){
    float wv = W2[k*128 + dd2];
    #pragma unroll
    for (int i=0;i<8;i++) o[i] = fmaf(hid[half*8+i][k], wv, o[i]);
  }
  #pragma unroll
  for (int i=0;i<8;i++) outp[(size_t)(e0 + half*8 + i)*128 + dd2] = o[i];
}

// ---------------- final MLP for nodes ----------------
__global__ __launch_bounds__(256) void k_fnode(const float* __restrict__ h2,
    const float* __restrict__ W1, const float* __restrict__ b1,
    const float* __restrict__ W2, const float* __restrict__ b2, float* __restrict__ outp){
  __shared__ float eo[16][128];
  __shared__ float hid[16][256];
  int tid = threadIdx.x;
  int r0 = blockIdx.x*16;
  for (int s=0;s<8;s++){
    int flat = tid + s*256; int el = flat>>7; int d = flat&127;
    eo[el][d] = h2[(size_t)(r0+el)*128 + d];
  }
  __syncthreads();
  float h[16];
  { float bb = b1[tid];
    #pragma unroll
    for (int e2=0;e2<16;e2++) h[e2] = bb; }
  for (int d2=0; d2<128; d2++){
    float wv = W1[d2*256 + tid];
    #pragma unroll
    for (int e2=0;e2<16;e2++) h[e2] = fmaf(eo[e2][d2], wv, h[e2]);
  }
  #pragma unroll
  for (int e2=0;e2<16;e2++) hid[e2][tid] = fmaxf(h[e2], 0.f);
  __syncthreads();
  int dd2 = tid & 127, half = tid >> 7;
  float o[8];
  { float bo = b2[dd2];
    #pragma unroll
    for (int i=0;i<8;i++) o[i] = bo; }
  for (int k=0;k<256;k++){
    float wv = W2[k*128 + dd2];
    #pragma unroll
    for (int i=0;i<8;i++) o[i] = fmaf(hid[half*8+i][k], wv, o[i]);
  }
  #pragma unroll
  for (int i=0;i<8;i++) outp[(size_t)(r0 + half*8 + i)*128 + dd2] = o[i];
}

// ---------------- graph_attr ----------------
__global__ void k_graph(const float* __restrict__ node_out, float* __restrict__ gout){
  int b = blockIdx.x, d = threadIdx.x;
  float s = 0.f;
  for (int i=0;i<64;i++) s += node_out[(size_t)(b*64+i)*128 + d];
  gout[b*128 + d] = s * (1.f/64.f);
}

extern "C" void kernel_launch(void* const* d_in, const int* in_sizes, int n_in,
                              void* d_out, int out_size, void* d_ws, size_t ws_size,
                              hipStream_t stream) {
  const int*   edge_index = (const int*)d_in[1];
  const int*   edge_attr  = (const int*)d_in[2];
  const float* t        = (const float*)d_in[3];
  const float* edge_emb = (const float*)d_in[5];
  const float* temb_W1  = (const float*)d_in[6];
  const float* temb_b1  = (const float*)d_in[7];
  const float* temb_W2  = (const float*)d_in[8];
  const float* temb_b2  = (const float*)d_in[9];
  const float* ein_W1   = (const float*)d_in[14];
  const float* ein_b1   = (const float*)d_in[15];
  const float* ein_W2   = (const float*)d_in[16];
  const float* ein_b2   = (const float*)d_in[17];
  const float* conv_W1  = (const float*)d_in[18];
  const float* conv_b1  = (const float*)d_in[19];
  const float* conv_g1  = (const float*)d_in[20];
  const float* conv_bt1 = (const float*)d_in[21];
  const float* conv_W2  = (const float*)d_in[22];
  const float* conv_b2  = (const float*)d_in[23];
  const float* conv_g2  = (const float*)d_in[24];
  const float* conv_bt2 = (const float*)d_in[25];
  const float* mlp_W1   = (const float*)d_in[26];
  const float* mlp_b1   = (const float*)d_in[27];
  const float* mlp_W2   = (const float*)d_in[28];
  const float* mlp_b2   = (const float*)d_in[29];
  const float* fn_W1    = (const float*)d_in[30];
  const float* fn_b1    = (const float*)d_in[31];
  const float* fn_W2    = (const float*)d_in[32];
  const float* fn_b2    = (const float*)d_in[33];

  float* ws  = (float*)d_ws;
  float* tt  = ws;                   // 4096
  float* enc = ws + 4096;            // 2048
  float* ym  = ws + 6144;            // up to 262144
  float* h2  = ws + 268288;          // up to 262144
  __bf16* WT = (__bf16*)(ws + 530432);  // 409600 bf16 (=204800 f32)
  const size_t HDRF = 1048576;       // 4 MB of floats reserved

  size_t availF = ws_size / sizeof(float);
  const int cands[6] = {32, 16, 8, 4, 2, 1};
  int C = 1;
  for (int i = 0; i < 6; i++){
    if (HDRF + 4ull * (size_t)cands[i] * 524288ull <= availF){ C = cands[i]; break; }
  }
  const size_t PCF = (size_t)C * 524288;  // f32 elems per plane buffer
  float* Xp = ws + HDRF;                  // C planes, f32 (S-layout)
  __bf16* bfb = (__bf16*)(Xp + PCF);
  __bf16* An  = bfb;
  __bf16* At  = An  + PCF;
  __bf16* Xn  = At  + PCF;
  __bf16* Xt  = Xn  + PCF;
  __bf16* X1t = Xt  + PCF;
  __bf16* X2t = X1t + PCF;
  float* outf = (float*)d_out;

  k_temb<<<NB, DD, 0, stream>>>(t, temb_W1, temb_b1, temb_W2, temb_b2, tt);
  k_edgeenc<<<16, 256, 0, stream>>>(edge_emb, ein_W1, ein_b1, ein_W2, ein_b2, enc);
  k_wprep<<<13, 256, 0, stream>>>(conv_W1, conv_W2, mlp_W1, WT);

  for (int b0 = 0; b0 < NB; b0 += C){
    hipMemsetAsync(Xp, 0, PCF*sizeof(float), stream);
    k_scatter<<<C*256, 256, 0, stream>>>(edge_index, edge_attr, enc, tt, Xp, b0);
    k_prep<<<C*128, 256, 0, stream>>>(Xp, At, An);

    for (int l=0; l<LAYERS; l++){
      const __bf16* Xn_l = (l==0) ? An : Xn;
      const __bf16* Xt_l = (l==0) ? At : Xt;
      k_einsum<<<C*64, 256, 0, stream>>>(An, At, Xn_l, Xt_l, X1t, X2t);
      k_convm<384,0><<<C*32, 256, 0, stream>>>(Xt_l, X1t, X2t, WT + (size_t)l*49152,
          conv_b1 + l*DD, conv_g1 + l*DD, conv_bt1 + l*DD, X1t, nullptr);
      k_convm<128,1><<<C*32, 256, 0, stream>>>(X1t, nullptr, nullptr, WT + 294912 + (size_t)l*16384,
          conv_b2 + l*DD, conv_g2 + l*DD, conv_bt2 + l*DD, Xt, Xp);
      k_transpose<<<C*128, 256, 0, stream>>>(Xt, Xn);
    }

    k_sym<<<C*128, 256, 0, stream>>>(Xp, Xt);
    k_convm<128,2><<<C*32, 256, 0, stream>>>(Xt, nullptr, nullptr, WT + 393216,
        mlp_b1, nullptr, nullptr, X1t, nullptr);
    k_ymean<<<C*32, 256, 0, stream>>>(X1t, ym);
    k_h2<<<C*64, 128, 0, stream>>>(ym, mlp_W2, mlp_b2, h2);
    k_fedge<<<C*32, 256, 0, stream>>>(Xp, edge_index, fn_W1, fn_b1, fn_W2, fn_b2, outf + 262144, b0);
    k_fnode<<<C*4, 256, 0, stream>>>(h2, fn_W1, fn_b1, fn_W2, fn_b2, outf + (size_t)b0*64*DD);
    k_graph<<<C, DD, 0, stream>>>(outf + (size_t)b0*64*DD, outf + 2359296 + b0*DD);
  }
}

// Round 4
// 825.833 us; speedup vs baseline: 2.7982x; 1.6370x over previous
//
#include <hip/hip_runtime.h>
#include <hip/hip_bf16.h>
#include <math.h>

#define NB 32
#define NNODE 64
#define DD 128
#define NSQ 4096
#define EDGES 16384
#define LAYERS 6

typedef __bf16 bf16x8 __attribute__((ext_vector_type(8)));
typedef float f32x4 __attribute__((ext_vector_type(4)));

__device__ __forceinline__ float silu_f(float x){ return x / (1.f + __expf(-x)); }
__device__ __forceinline__ float bf2f(unsigned short h){
  union{unsigned int u; float f;} x; x.u = ((unsigned int)h)<<16; return x.f;
}

// ---------------- time embedding ----------------
__global__ void k_temb(const float* __restrict__ t, const float* __restrict__ W1,
                       const float* __restrict__ b1, const float* __restrict__ W2,
                       const float* __restrict__ b2, float* __restrict__ tt){
  int b = blockIdx.x, d = threadIdx.x;
  __shared__ float h[DD];
  float v = t[b]*W1[d] + b1[d];
  h[d] = silu_f(v);
  __syncthreads();
  float acc = b2[d];
  #pragma unroll 4
  for (int k=0;k<DD;k++) acc = fmaf(h[k], W2[k*DD+d], acc);
  tt[b*DD+d] = silu_f(acc);
}

// ---------------- edge-type table (16 types) ----------------
__global__ void k_edgeenc(const float* __restrict__ emb, const float* __restrict__ W1,
                          const float* __restrict__ b1, const float* __restrict__ W2,
                          const float* __restrict__ b2, float* __restrict__ enc){
  int et = blockIdx.x, tid = threadIdx.x;
  __shared__ float e0[DD];
  __shared__ float hid[2*DD];
  if (tid < DD) e0[tid] = emb[et*DD + tid];
  __syncthreads();
  float a = b1[tid];
  for (int d2=0; d2<DD; d2++) a = fmaf(e0[d2], W1[d2*256 + tid], a);
  hid[tid] = fmaxf(a, 0.f);
  __syncthreads();
  if (tid < DD){
    float o = b2[tid];
    for (int k=0;k<256;k++) o = fmaf(hid[k], W2[k*DD + tid], o);
    enc[et*DD + tid] = o;
  }
}

// ---------------- histogram scatter: 1 atomic per edge ----------------
__global__ void k_cnt(const int* __restrict__ ei, const int* __restrict__ attr,
                      unsigned int* __restrict__ cnt, int b0){
  int e = b0*512 + blockIdx.x*256 + threadIdx.x;
  int s = ei[e], dN = ei[EDGES+e];
  int g = (s>>6) - b0, u = s&63, v = dN&63;
  atomicAdd(&cnt[((size_t)g*4096 + v*64 + u)*16 + attr[e]], 1u);
}

// ---------------- expand: A_S[d][cell] = tt[g][d] * sum_et cnt[cell][et]*enc[et][d] ----------------
__global__ __launch_bounds__(256) void k_expand(const unsigned int* __restrict__ cnt,
    const float* __restrict__ enc, const float* __restrict__ tt,
    __bf16* __restrict__ A_S, int b0){
  __shared__ float encs[16][128];
  __shared__ float ttl[128];
  __shared__ __bf16 tb[8][256];
  int g = blockIdx.x >> 4;
  int cell0 = (blockIdx.x & 15) << 8;
  int tid = threadIdx.x;
  for (int s = tid; s < 2048; s += 256) encs[s>>7][s&127] = enc[s];
  if (tid < 128) ttl[tid] = tt[(b0+g)*128 + tid];
  unsigned int c16[16];
  { const uint4* src = (const uint4*)(cnt + ((size_t)g*4096 + cell0 + tid)*16);
    uint4 a = src[0], b = src[1], c = src[2], d = src[3];
    c16[0]=a.x; c16[1]=a.y; c16[2]=a.z; c16[3]=a.w;
    c16[4]=b.x; c16[5]=b.y; c16[6]=b.z; c16[7]=b.w;
    c16[8]=c.x; c16[9]=c.y; c16[10]=c.z; c16[11]=c.w;
    c16[12]=d.x; c16[13]=d.y; c16[14]=d.z; c16[15]=d.w; }
  __syncthreads();
  for (int dc=0; dc<16; dc++){
    int d0 = dc*8;
    float vals[8] = {0.f,0.f,0.f,0.f,0.f,0.f,0.f,0.f};
    #pragma unroll
    for (int et=0; et<16; et++){
      unsigned int c = c16[et];
      if (c){
        float fc = (float)c;
        #pragma unroll
        for (int dd=0; dd<8; dd++) vals[dd] = fmaf(fc, encs[et][d0+dd], vals[dd]);
      }
    }
    #pragma unroll
    for (int dd=0; dd<8; dd++) tb[dd][tid] = (__bf16)(vals[dd]*ttl[d0+dd]);
    __syncthreads();
    { int dd = tid>>5, seg = tid&31;
      uint4 v = *(const uint4*)&tb[dd][seg*8];
      *(uint4*)(A_S + ((size_t)(g*128 + d0 + dd)<<12) + cell0 + seg*8) = v; }
    __syncthreads();
  }
}

// ---------------- bf16 plane transpose (S <-> N) ----------------
__global__ __launch_bounds__(256) void k_transpose(const __bf16* __restrict__ src, __bf16* __restrict__ dst){
  __shared__ unsigned short L[64][65];
  size_t base = (size_t)blockIdx.x * 4096;
  int t = threadIdx.x;
  int f = t*16, r = f>>6, c = f&63;
  union { unsigned short h[16]; uint4 u[2]; } in;
  in.u[0] = *(const uint4*)((const unsigned short*)src + base + f);
  in.u[1] = *(const uint4*)((const unsigned short*)src + base + f + 8);
  #pragma unroll
  for (int e=0;e<16;e++) L[r][c+e] = in.h[e];
  __syncthreads();
  union { unsigned short h[16]; uint4 u[2]; } o;
  #pragma unroll
  for (int e=0;e<16;e++) o.h[e] = L[c+e][r];
  *(uint4*)((unsigned short*)dst + base + f)     = o.u[0];
  *(uint4*)((unsigned short*)dst + base + f + 8) = o.u[1];
}

// ---------------- weight prep: Wt[fo][K] = W^T in bf16 ----------------
__global__ __launch_bounds__(256) void k_wprep(const float* __restrict__ W1, const float* __restrict__ W2,
                                               const float* __restrict__ Wm, __bf16* __restrict__ WT){
  int b = blockIdx.x, t = threadIdx.x;
  const float* src; __bf16* dst; int K;
  if (b < 6){ src = W1 + (size_t)b*384*128; dst = WT + (size_t)b*49152; K = 384; }
  else if (b < 12){ src = W2 + (size_t)(b-6)*128*128; dst = WT + 294912 + (size_t)(b-6)*16384; K = 128; }
  else { src = Wm; dst = WT + 393216; K = 128; }
  __shared__ float L[64][129];
  for (int k0 = 0; k0 < K; k0 += 64){
    __syncthreads();
    int r = t>>2, c = (t&3)*32;
    #pragma unroll
    for (int e=0;e<32;e+=4){
      float4 x = *(const float4*)(src + (size_t)(k0+r)*128 + c + e);
      L[r][c+e]=x.x; L[r][c+e+1]=x.y; L[r][c+e+2]=x.z; L[r][c+e+3]=x.w;
    }
    __syncthreads();
    int fo = t>>1, kk = (t&1)*32;
    union { __bf16 h[32]; uint4 u[4]; } o;
    #pragma unroll
    for (int e=0;e<32;e++) o.h[e] = (__bf16)L[kk+e][fo];
    uint4* d4 = (uint4*)(dst + (size_t)fo*K + k0 + kk);
    d4[0]=o.u[0]; d4[1]=o.u[1]; d4[2]=o.u[2]; d4[3]=o.u[3];
  }
}

// ---------------- einsum (MFMA): X1_S, X2_S from {A_N,A_S,X_N,X_S} ----------------
__global__ __launch_bounds__(256) void k_einsum(const __bf16* __restrict__ An, const __bf16* __restrict__ At,
                                                const __bf16* __restrict__ Xn, const __bf16* __restrict__ Xt,
                                                __bf16* __restrict__ X1t, __bf16* __restrict__ X2t){
  __shared__ __bf16 S[8][4096];
  int tid = threadIdx.x;
  size_t p0 = (size_t)blockIdx.x * 2;
  const __bf16* srcs[4] = {An, At, Xn, Xt};
  #pragma unroll
  for (int bI = 0; bI < 8; bI++){
    const uint4* g = (const uint4*)(srcs[bI>>1] + (p0 + (bI&1))*4096);
    #pragma unroll
    for (int s = 0; s < 2; s++){
      int idx = tid + s*256;
      uint4 v = g[idx];
      int row = idx>>3; int slot = idx&7;
      *(uint4*)&S[bI][row*64 + ((slot ^ (row&7))<<3)] = v;
    }
  }
  __syncthreads();
  int w = tid>>6, lane = tid&63;
  int pl = w>>1, pr = w&1;
  const __bf16* M  = pr ? S[4+pl] : S[0+pl];
  const __bf16* Bt = pr ? S[2+pl] : S[6+pl];
  f32x4 acc[4][4];
  #pragma unroll
  for (int a=0;a<4;a++)
    #pragma unroll
    for(int b=0;b<4;b++) acc[a][b] = (f32x4){0.f,0.f,0.f,0.f};
  int lr = lane&15, lq = lane>>4;
  #pragma unroll
  for (int ks=0;ks<2;ks++){
    bf16x8 af[4], bfr[4];
    #pragma unroll
    for (int mt=0;mt<4;mt++){ int r = mt*16+lr; af[mt] = *(const bf16x8*)&M[r*64 + (((ks*4+lq) ^ (r&7))<<3)]; }
    #pragma unroll
    for (int nt=0;nt<4;nt++){ int r = nt*16+lr; bfr[nt] = *(const bf16x8*)&Bt[r*64 + (((ks*4+lq) ^ (r&7))<<3)]; }
    #pragma unroll
    for (int mt=0;mt<4;mt++)
      #pragma unroll
      for (int nt=0;nt<4;nt++)
        acc[mt][nt] = __builtin_amdgcn_mfma_f32_16x16x32_bf16(af[mt], bfr[nt], acc[mt][nt], 0,0,0);
  }
  __bf16* OUT = (pr ? X2t : X1t) + (p0+pl)*4096;
  #pragma unroll
  for (int mt=0;mt<4;mt++)
    #pragma unroll
    for (int nt=0;nt<4;nt++){
      int col = nt*16 + lr; int row0 = mt*16 + lq*4;
      union { __bf16 h[4]; uint2 u; } o;
      #pragma unroll
      for (int r=0;r<4;r++) o.h[r] = (__bf16)acc[mt][nt][r];
      *(uint2*)&OUT[col*64 + row0] = o.u;
    }
}

// ---------------- fused conv1+LN1+relu+conv2+LN2+relu+residual ----------------
__global__ __launch_bounds__(256) void k_layer(const __bf16* __restrict__ Xold,
    const __bf16* __restrict__ X1, const __bf16* __restrict__ X2,
    const __bf16* __restrict__ W1t, const __bf16* __restrict__ W2t,
    const float* __restrict__ b1v, const float* __restrict__ g1v, const float* __restrict__ bt1v,
    const float* __restrict__ b2v, const float* __restrict__ g2v, const float* __restrict__ bt2v,
    __bf16* __restrict__ Xnew){
  __shared__ __bf16 Wc[128*32];
  __shared__ __bf16 Cc[128*32];
  __shared__ __bf16 y1T[128*128];
  __shared__ float redS[4][128], redQ[4][128];
  __shared__ float stats[2][128];
  int tid = threadIdx.x, w = tid>>6, lane = tid&63, lr = lane&15, lq = lane>>4;
  int colTile = blockIdx.x << 7;
  int bl = colTile >> 12;
  int colInB = colTile & 4095;
  f32x4 acc[2][8];
  #pragma unroll
  for (int a=0;a<2;a++)
    #pragma unroll
    for (int b=0;b<8;b++) acc[a][b] = (f32x4){0.f,0.f,0.f,0.f};

  // ---- GEMM1: K=384 ----
  for (int ks=0; ks<12; ks++){
    __syncthreads();
    { int fo = tid>>1, half = tid&1;
      const uint4* src = (const uint4*)(W1t + (size_t)fo*384 + ks*32 + half*16);
      uint4 v0 = src[0], v1 = src[1];
      *(uint4*)&Wc[fo*32 + (((half*2+0) ^ (fo&3))<<3)] = v0;
      *(uint4*)&Wc[fo*32 + (((half*2+1) ^ (fo&3))<<3)] = v1;
    }
    { int fr = tid>>3, seg = tid&7;
      int fi = ks*32 + fr;
      const __bf16* T = (fi<128)? Xold : (fi<256? X1 : X2);
      int d = fi & 127;
      const __bf16* src = T + ((size_t)(bl*128 + d)<<12) + colInB + seg*16;
      union { __bf16 h[16]; uint4 u[2]; } v;
      v.u[0] = *(const uint4*)src;
      v.u[1] = *(const uint4*)(src + 8);
      #pragma unroll
      for (int e=0;e<16;e++){
        int col = seg*16 + e;
        Cc[col*32 + (fr ^ ((col&3)<<3))] = v.h[e];
      }
    }
    __syncthreads();
    bf16x8 af[2], bfr[8];
    #pragma unroll
    for (int mt=0;mt<2;mt++){ int fo = w*32+mt*16+lr; af[mt] = *(const bf16x8*)&Wc[fo*32 + ((lq ^ (fo&3))<<3)]; }
    #pragma unroll
    for (int nt=0;nt<8;nt++){ int cr = nt*16+lr; bfr[nt] = *(const bf16x8*)&Cc[cr*32 + ((lq ^ (cr&3))<<3)]; }
    #pragma unroll
    for (int mt=0;mt<2;mt++)
      #pragma unroll
      for (int nt=0;nt<8;nt++)
        acc[mt][nt] = __builtin_amdgcn_mfma_f32_16x16x32_bf16(af[mt], bfr[nt], acc[mt][nt], 0,0,0);
  }

  // ---- bias1 + LN1 ----
  #pragma unroll
  for (int mt=0;mt<2;mt++){
    #pragma unroll
    for (int r=0;r<4;r++){
      float bv = b1v[w*32 + mt*16 + lq*4 + r];
      #pragma unroll
      for (int nt=0;nt<8;nt++) acc[mt][nt][r] += bv;
    }
  }
  {
    float cs[8], cq[8];
    #pragma unroll
    for (int nt=0;nt<8;nt++){ cs[nt]=0.f; cq[nt]=0.f; }
    #pragma unroll
    for (int mt=0;mt<2;mt++)
      #pragma unroll
      for (int nt=0;nt<8;nt++)
        #pragma unroll
        for (int r=0;r<4;r++){ float v = acc[mt][nt][r]; cs[nt] += v; cq[nt] = fmaf(v,v,cq[nt]); }
    #pragma unroll
    for (int nt=0;nt<8;nt++){
      cs[nt] += __shfl_xor(cs[nt], 16); cq[nt] += __shfl_xor(cq[nt], 16);
      cs[nt] += __shfl_xor(cs[nt], 32); cq[nt] += __shfl_xor(cq[nt], 32);
    }
    if (lq == 0){
      #pragma unroll
      for (int nt=0;nt<8;nt++){ redS[w][nt*16+lr] = cs[nt]; redQ[w][nt*16+lr] = cq[nt]; }
    }
  }
  __syncthreads();
  if (tid < 128){
    float S = redS[0][tid]+redS[1][tid]+redS[2][tid]+redS[3][tid];
    float Q = redQ[0][tid]+redQ[1][tid]+redQ[2][tid]+redQ[3][tid];
    float m = S*(1.f/128.f);
    float var = Q*(1.f/128.f) - m*m;
    stats[0][tid] = m; stats[1][tid] = rsqrtf(var + 1e-5f);
  }
  __syncthreads();
  // ---- LN1 apply + relu -> y1T (swizzled) ----
  #pragma unroll
  for (int mt=0;mt<2;mt++){
    int fo1b = w*32 + mt*16 + lq*4;
    float ga[4], be[4];
    #pragma unroll
    for (int r=0;r<4;r++){ ga[r] = g1v[fo1b+r]; be[r] = bt1v[fo1b+r]; }
    #pragma unroll
    for (int nt=0;nt<8;nt++){
      int col = nt*16 + lr;
      union { __bf16 h[4]; uint2 u; } o;
      #pragma unroll
      for (int r=0;r<4;r++){
        float xx = (acc[mt][nt][r] - stats[0][col]) * stats[1][col] * ga[r] + be[r];
        o.h[r] = (__bf16)fmaxf(xx, 0.f);
      }
      *(uint2*)&y1T[col*128 + (fo1b ^ ((col&15)<<3))] = o.u;
    }
  }
  __syncthreads();

  // ---- GEMM2: K=128 from y1T ----
  f32x4 acc2[2][8];
  #pragma unroll
  for (int a=0;a<2;a++)
    #pragma unroll
    for (int b=0;b<8;b++) acc2[a][b] = (f32x4){0.f,0.f,0.f,0.f};
  for (int ks2=0; ks2<4; ks2++){
    __syncthreads();
    { int fo = tid>>1, half = tid&1;
      const uint4* src = (const uint4*)(W2t + (size_t)fo*128 + ks2*32 + half*16);
      uint4 v0 = src[0], v1 = src[1];
      *(uint4*)&Wc[fo*32 + (((half*2+0) ^ (fo&3))<<3)] = v0;
      *(uint4*)&Wc[fo*32 + (((half*2+1) ^ (fo&3))<<3)] = v1;
    }
    __syncthreads();
    bf16x8 af[2], bfr[8];
    #pragma unroll
    for (int mt=0;mt<2;mt++){ int fo = w*32+mt*16+lr; af[mt] = *(const bf16x8*)&Wc[fo*32 + ((lq ^ (fo&3))<<3)]; }
    #pragma unroll
    for (int nt=0;nt<8;nt++){ int cr = nt*16+lr; bfr[nt] = *(const bf16x8*)&y1T[cr*128 + ((ks2*32 + lq*8) ^ ((cr&15)<<3))]; }
    #pragma unroll
    for (int mt=0;mt<2;mt++)
      #pragma unroll
      for (int nt=0;nt<8;nt++)
        acc2[mt][nt] = __builtin_amdgcn_mfma_f32_16x16x32_bf16(af[mt], bfr[nt], acc2[mt][nt], 0,0,0);
  }

  // ---- bias2 + LN2 ----
  #pragma unroll
  for (int mt=0;mt<2;mt++){
    #pragma unroll
    for (int r=0;r<4;r++){
      float bv = b2v[w*32 + mt*16 + lq*4 + r];
      #pragma unroll
      for (int nt=0;nt<8;nt++) acc2[mt][nt][r] += bv;
    }
  }
  {
    float cs[8], cq[8];
    #pragma unroll
    for (int nt=0;nt<8;nt++){ cs[nt]=0.f; cq[nt]=0.f; }
    #pragma unroll
    for (int mt=0;mt<2;mt++)
      #pragma unroll
      for (int nt=0;nt<8;nt++)
        #pragma unroll
        for (int r=0;r<4;r++){ float v = acc2[mt][nt][r]; cs[nt] += v; cq[nt] = fmaf(v,v,cq[nt]); }
    #pragma unroll
    for (int nt=0;nt<8;nt++){
      cs[nt] += __shfl_xor(cs[nt], 16); cq[nt] += __shfl_xor(cq[nt], 16);
      cs[nt] += __shfl_xor(cs[nt], 32); cq[nt] += __shfl_xor(cq[nt], 32);
    }
    if (lq == 0){
      #pragma unroll
      for (int nt=0;nt<8;nt++){ redS[w][nt*16+lr] = cs[nt]; redQ[w][nt*16+lr] = cq[nt]; }
    }
  }
  __syncthreads();
  if (tid < 128){
    float S = redS[0][tid]+redS[1][tid]+redS[2][tid]+redS[3][tid];
    float Q = redQ[0][tid]+redQ[1][tid]+redQ[2][tid]+redQ[3][tid];
    float m = S*(1.f/128.f);
    float var = Q*(1.f/128.f) - m*m;
    stats[0][tid] = m; stats[1][tid] = rsqrtf(var + 1e-5f);
  }
  __syncthreads();
  // ---- LN2 apply + relu + residual -> Xnew ----
  #pragma unroll
  for (int mt=0;mt<2;mt++){
    #pragma unroll
    for (int r=0;r<4;r++){
      int fo = w*32 + mt*16 + lq*4 + r;
      float ga = g2v[fo], be = bt2v[fo];
      size_t rowb = ((size_t)(bl*128 + fo)<<12) + colInB;
      #pragma unroll
      for (int nt=0;nt<8;nt++){
        int cp = nt*16 + lr;
        float xx = (acc2[mt][nt][r] - stats[0][cp]) * stats[1][cp] * ga + be;
        float o = fmaxf(xx, 0.f);
        float old = (float)Xold[rowb + cp];
        Xnew[rowb + cp] = (__bf16)(o + old);
      }
    }
  }
}

// ---------------- symmetrize: out = in + in^T (per plane, bf16) ----------------
__global__ __launch_bounds__(256) void k_sym(const __bf16* __restrict__ Xin, __bf16* __restrict__ Xout){
  __shared__ float P[64][65];
  size_t base = (size_t)blockIdx.x * 4096;
  int tid = threadIdx.x;
  int f = tid*16, r = f>>6, c = f&63;
  union { __bf16 h[16]; uint4 u[2]; } in;
  in.u[0] = *(const uint4*)(Xin + base + f);
  in.u[1] = *(const uint4*)(Xin + base + f + 8);
  #pragma unroll
  for (int e=0;e<16;e++) P[r][c+e] = (float)in.h[e];
  __syncthreads();
  union { __bf16 h[16]; uint4 u[2]; } o;
  #pragma unroll
  for (int e=0;e<16;e++) o.h[e] = (__bf16)(P[r][c+e] + P[c+e][r]);
  *(uint4*)(Xout + base + f)     = o.u[0];
  *(uint4*)(Xout + base + f + 8) = o.u[1];
}

// ---------------- to node-major: NM[g*4096+cell][d] = S[g*128+d][cell] ----------------
__global__ __launch_bounds__(256) void k_tonm(const __bf16* __restrict__ S, __bf16* __restrict__ NM){
  __shared__ unsigned short L[64][65];
  int b = blockIdx.x;
  int g = b >> 7, dh = (b>>6)&1, cc = b&63;
  int cell0 = cc*64, d0 = dh*64;
  int tid = threadIdx.x;
  int r = tid>>2, c = (tid&3)*16;
  union { unsigned short h[16]; uint4 u[2]; } in;
  const unsigned short* src = (const unsigned short*)S + ((size_t)(g*128 + d0 + r)<<12) + cell0 + c;
  in.u[0] = *(const uint4*)src;
  in.u[1] = *(const uint4*)(src + 8);
  #pragma unroll
  for (int e=0;e<16;e++) L[r][c+e] = in.h[e];
  __syncthreads();
  union { unsigned short h[16]; uint4 u[2]; } o;
  int cr = tid>>2, dc = (tid&3)*16;
  #pragma unroll
  for (int e=0;e<16;e++) o.h[e] = L[dc+e][cr];
  unsigned short* dst = (unsigned short*)NM + (size_t)(g*4096 + cell0 + cr)*128 + d0 + dc;
  *(uint4*)dst       = o.u[0];
  *(uint4*)(dst + 8) = o.u[1];
}

// ---------------- mlp hidden: silu(Xsym @ W1m + b1m) (MFMA, per-plane out) ----------------
__global__ __launch_bounds__(256) void k_mlph(const __bf16* __restrict__ in0,
    const __bf16* __restrict__ Wt, const float* __restrict__ bias, __bf16* __restrict__ outb){
  __shared__ __bf16 Wc[128*32];
  __shared__ __bf16 Cc[128*32];
  int tid = threadIdx.x, w = tid>>6, lane = tid&63, lr = lane&15, lq = lane>>4;
  int colTile = blockIdx.x << 7;
  int bl = colTile >> 12;
  int colInB = colTile & 4095;
  f32x4 acc[2][8];
  #pragma unroll
  for (int a=0;a<2;a++)
    #pragma unroll
    for (int b=0;b<8;b++) acc[a][b] = (f32x4){0.f,0.f,0.f,0.f};
  for (int ks=0; ks<4; ks++){
    __syncthreads();
    { int fo = tid>>1, half = tid&1;
      const uint4* src = (const uint4*)(Wt + (size_t)fo*128 + ks*32 + half*16);
      uint4 v0 = src[0], v1 = src[1];
      *(uint4*)&Wc[fo*32 + (((half*2+0) ^ (fo&3))<<3)] = v0;
      *(uint4*)&Wc[fo*32 + (((half*2+1) ^ (fo&3))<<3)] = v1;
    }
    { int fr = tid>>3, seg = tid&7;
      int d = ks*32 + fr;
      const __bf16* src = in0 + ((size_t)(bl*128 + d)<<12) + colInB + seg*16;
      union { __bf16 h[16]; uint4 u[2]; } v;
      v.u[0] = *(const uint4*)src;
      v.u[1] = *(const uint4*)(src + 8);
      #pragma unroll
      for (int e=0;e<16;e++){
        int col = seg*16 + e;
        Cc[col*32 + (fr ^ ((col&3)<<3))] = v.h[e];
      }
    }
    __syncthreads();
    bf16x8 af[2], bfr[8];
    #pragma unroll
    for (int mt=0;mt<2;mt++){ int fo = w*32+mt*16+lr; af[mt] = *(const bf16x8*)&Wc[fo*32 + ((lq ^ (fo&3))<<3)]; }
    #pragma unroll
    for (int nt=0;nt<8;nt++){ int cr = nt*16+lr; bfr[nt] = *(const bf16x8*)&Cc[cr*32 + ((lq ^ (cr&3))<<3)]; }
    #pragma unroll
    for (int mt=0;mt<2;mt++)
      #pragma unroll
      for (int nt=0;nt<8;nt++)
        acc[mt][nt] = __builtin_amdgcn_mfma_f32_16x16x32_bf16(af[mt], bfr[nt], acc[mt][nt], 0,0,0);
  }
  #pragma unroll
  for (int mt=0;mt<2;mt++){
    #pragma unroll
    for (int r=0;r<4;r++){
      int fo = w*32 + mt*16 + lq*4 + r;
      float bv = bias[fo];
      size_t rowb = ((size_t)(bl*128 + fo)<<12) + colInB;
      #pragma unroll
      for (int nt=0;nt<8;nt++){
        int cp = nt*16 + lr;
        outb[rowb + cp] = (__bf16)silu_f(acc[mt][nt][r] + bv);
      }
    }
  }
}

// ---------------- mean over j (S-layout hidden planes) ----------------
__global__ __launch_bounds__(256) void k_ymean(const __bf16* __restrict__ Y, float* __restrict__ ym){
  int tid = threadIdx.x; int w = tid>>6, lane = tid&63;
  int p = blockIdx.x*4 + w;
  const __bf16* pl = Y + (size_t)p*4096;
  float s = 0.f;
  for (int j=0;j<64;j++) s += (float)pl[j*64 + lane];
  int bl = p>>7, d = p&127;
  ym[(size_t)(bl*64 + lane)*128 + d] = s*(1.f/64.f);
}

// ---------------- h2 = ym @ mlp_W2 + b2 ----------------
__global__ void k_h2(const float* __restrict__ ym, const float* __restrict__ W2,
                     const float* __restrict__ b2, float* __restrict__ h2){
  int row = blockIdx.x, fo = threadIdx.x;
  __shared__ float rr[128];
  rr[fo] = ym[(size_t)row*128 + fo];
  __syncthreads();
  float a = b2[fo];
  #pragma unroll 4
  for (int k=0;k<128;k++) a = fmaf(rr[k], W2[k*128+fo], a);
  h2[(size_t)row*128+fo] = a;
}

// ---------------- final MLP for edges (contiguous gather from NM) ----------------
__global__ __launch_bounds__(256) void k_fedge(const __bf16* __restrict__ NM, const int* __restrict__ ei,
    const float* __restrict__ W1, const float* __restrict__ b1,
    const float* __restrict__ W2, const float* __restrict__ b2, float* __restrict__ outp, int b0){
  __shared__ float eo[16][128];
  __shared__ float hid[16][256];
  __shared__ int cells[16];
  int tid = threadIdx.x;
  int e0 = b0*512 + blockIdx.x*16;
  if (tid < 16){
    int e = e0 + tid;
    int s = ei[e], dN = ei[EDGES + e];
    cells[tid] = ((s>>6) - b0)*4096 + (dN&63)*64 + (s&63);
  }
  __syncthreads();
  { int el = tid>>4, d0 = (tid&15)*8;
    const unsigned short* src = (const unsigned short*)NM + (size_t)cells[el]*128 + d0;
    union { unsigned short h[8]; uint4 u; } v;
    v.u = *(const uint4*)src;
    #pragma unroll
    for (int e2=0;e2<8;e2++) eo[el][d0+e2] = bf2f(v.h[e2]);
  }
  __syncthreads();
  float h[16];
  { float bb = b1[tid];
    #pragma unroll
    for (int e2=0;e2<16;e2++) h[e2] = bb; }
  for (int d2=0; d2<128; d2++){
    float wv = W1[d2*256 + tid];
    #pragma unroll
    for (int e2=0;e2<16;e2++) h[e2] = fmaf(eo[e2][d2], wv, h[e2]);
  }
  #pragma unroll
  for (int e2=0;e2<16;e2++) hid[e2][tid] = fmaxf(h[e2], 0.f);
  __syncthreads();
  int dd2 = tid & 127, half = tid >> 7;
  float o[8];
  { float bo = b2[dd2];
    #pragma unroll
    for (int i=0;i<8;i++) o[i] = bo; }
  for (int k=0;k<256;k++){
    float wv = W2[k*128 + dd2];
    #pragma unroll
    for (int i=0;i<8;i++) o[i] = fmaf(hid[half*8+i][k], wv, o[i]);
  }
  #pragma unroll
  for (int i=0;i<8;i++) outp[(size_t)(e0 + half*8 + i)*128 + dd2] = o[i];
}

// ---------------- final MLP for nodes ----------------
__global__ __launch_bounds__(256) void k_fnode(const float* __restrict__ h2,
    const float* __restrict__ W1, const float* __restrict__ b1,
    const float* __restrict__ W2, const float* __restrict__ b2, float* __restrict__ outp){
  __shared__ float eo[16][128];
  __shared__ float hid[16][256];
  int tid = threadIdx.x;
  int r0 = blockIdx.x*16;
  for (int s=0;s<8;s++){
    int flat = tid + s*256; int el = flat>>7; int d = flat&127;
    eo[el][d] = h2[(size_t)(r0+el)*128 + d];
  }
  __syncthreads();
  float h[16];
  { float bb = b1[tid];
    #pragma unroll
    for (int e2=0;e2<16;e2++) h[e2] = bb; }
  for (int d2=0; d2<128; d2++){
    float wv = W1[d2*256 + tid];
    #pragma unroll
    for (int e2=0;e2<16;e2++) h[e2] = fmaf(eo[e2][d2], wv, h[e2]);
  }
  #pragma unroll
  for (int e2=0;e2<16;e2++) hid[e2][tid] = fmaxf(h[e2], 0.f);
  __syncthreads();
  int dd2 = tid & 127, half = tid >> 7;
  float o[8];
  { float bo = b2[dd2];
    #pragma unroll
    for (int i=0;i<8;i++) o[i] = bo; }
  for (int k=0;k<256;k++){
    float wv = W2[k*128 + dd2];
    #pragma unroll
    for (int i=0;i<8;i++) o[i] = fmaf(hid[half*8+i][k], wv, o[i]);
  }
  #pragma unroll
  for (int i=0;i<8;i++) outp[(size_t)(r0 + half*8 + i)*128 + dd2] = o[i];
}

// ---------------- graph_attr ----------------
__global__ void k_graph(const float* __restrict__ node_out, float* __restrict__ gout){
  int b = blockIdx.x, d = threadIdx.x;
  float s = 0.f;
  for (int i=0;i<64;i++) s += node_out[(size_t)(b*64+i)*128 + d];
  gout[b*128 + d] = s * (1.f/64.f);
}

extern "C" void kernel_launch(void* const* d_in, const int* in_sizes, int n_in,
                              void* d_out, int out_size, void* d_ws, size_t ws_size,
                              hipStream_t stream) {
  const int*   edge_index = (const int*)d_in[1];
  const int*   edge_attr  = (const int*)d_in[2];
  const float* t        = (const float*)d_in[3];
  const float* edge_emb = (const float*)d_in[5];
  const float* temb_W1  = (const float*)d_in[6];
  const float* temb_b1  = (const float*)d_in[7];
  const float* temb_W2  = (const float*)d_in[8];
  const float* temb_b2  = (const float*)d_in[9];
  const float* ein_W1   = (const float*)d_in[14];
  const float* ein_b1   = (const float*)d_in[15];
  const float* ein_W2   = (const float*)d_in[16];
  const float* ein_b2   = (const float*)d_in[17];
  const float* conv_W1  = (const float*)d_in[18];
  const float* conv_b1  = (const float*)d_in[19];
  const float* conv_g1  = (const float*)d_in[20];
  const float* conv_bt1 = (const float*)d_in[21];
  const float* conv_W2  = (const float*)d_in[22];
  const float* conv_b2  = (const float*)d_in[23];
  const float* conv_g2  = (const float*)d_in[24];
  const float* conv_bt2 = (const float*)d_in[25];
  const float* mlp_W1   = (const float*)d_in[26];
  const float* mlp_b1   = (const float*)d_in[27];
  const float* mlp_W2   = (const float*)d_in[28];
  const float* mlp_b2   = (const float*)d_in[29];
  const float* fn_W1    = (const float*)d_in[30];
  const float* fn_b1    = (const float*)d_in[31];
  const float* fn_W2    = (const float*)d_in[32];
  const float* fn_b2    = (const float*)d_in[33];

  float* ws  = (float*)d_ws;
  float* tt  = ws;                      // 4096
  float* enc = ws + 4096;               // 2048
  float* ym  = ws + 6144;               // 262144 max
  float* h2  = ws + 268288;             // 262144 max
  __bf16* WT = (__bf16*)(ws + 530432);  // 409600 bf16
  unsigned int* cnt = (unsigned int*)(ws + 735232);  // up to 2097152 u32
  const size_t HDRF = 2883584;          // floats reserved

  size_t availF = ws_size / sizeof(float);
  const int cands[6] = {32, 16, 8, 4, 2, 1};
  int C = 1;
  for (int i = 0; i < 6; i++){
    if (HDRF + 6ull * (size_t)cands[i] * 262144ull <= availF){ C = cands[i]; break; }
  }
  const size_t PCB = (size_t)C * 262144;   // f32-equiv per bf16 plane tensor
  __bf16* A_S = (__bf16*)(ws + HDRF);
  __bf16* A_N = (__bf16*)(ws + HDRF + PCB);
  __bf16* X_S = (__bf16*)(ws + HDRF + 2*PCB);
  __bf16* X_N = (__bf16*)(ws + HDRF + 3*PCB);
  __bf16* X1  = (__bf16*)(ws + HDRF + 4*PCB);
  __bf16* X2  = (__bf16*)(ws + HDRF + 5*PCB);
  float* outf = (float*)d_out;

  k_temb<<<NB, DD, 0, stream>>>(t, temb_W1, temb_b1, temb_W2, temb_b2, tt);
  k_edgeenc<<<16, 256, 0, stream>>>(edge_emb, ein_W1, ein_b1, ein_W2, ein_b2, enc);
  k_wprep<<<13, 256, 0, stream>>>(conv_W1, conv_W2, mlp_W1, WT);

  for (int b0 = 0; b0 < NB; b0 += C){
    hipMemsetAsync(cnt, 0, (size_t)C*4096*16*sizeof(unsigned int), stream);
    k_cnt<<<C*2, 256, 0, stream>>>(edge_index, edge_attr, cnt, b0);
    k_expand<<<C*16, 256, 0, stream>>>(cnt, enc, tt, A_S, b0);
    k_transpose<<<C*128, 256, 0, stream>>>(A_S, A_N);

    for (int l=0; l<LAYERS; l++){
      const __bf16* Xs_l = (l==0) ? A_S : X_S;
      const __bf16* Xn_l = (l==0) ? A_N : X_N;
      if (l > 0) k_transpose<<<C*128, 256, 0, stream>>>(X_S, X_N);
      k_einsum<<<C*64, 256, 0, stream>>>(A_N, A_S, Xn_l, Xs_l, X1, X2);
      k_layer<<<C*32, 256, 0, stream>>>(Xs_l, X1, X2,
          WT + (size_t)l*49152, WT + 294912 + (size_t)l*16384,
          conv_b1 + l*DD, conv_g1 + l*DD, conv_bt1 + l*DD,
          conv_b2 + l*DD, conv_g2 + l*DD, conv_bt2 + l*DD, X_S);
    }

    k_sym<<<C*128, 256, 0, stream>>>(X_S, X2);
    k_tonm<<<C*128, 256, 0, stream>>>(X2, X_N);
    k_mlph<<<C*32, 256, 0, stream>>>(X2, WT + 393216, mlp_b1, X1);
    k_ymean<<<C*32, 256, 0, stream>>>(X1, ym);
    k_h2<<<C*64, 128, 0, stream>>>(ym, mlp_W2, mlp_b2, h2);
    k_fedge<<<C*32, 256, 0, stream>>>(X_N, edge_index, fn_W1, fn_b1, fn_W2, fn_b2, outf + 262144, b0);
    k_fnode<<<C*4, 256, 0, stream>>>(h2, fn_W1, fn_b1, fn_W2, fn_b2, outf + (size_t)b0*64*DD);
    k_graph<<<C, DD, 0, stream>>>(outf + (size_t)b0*64*DD, outf + 2359296 + b0*DD);
  }
}

// Round 5
// 754.538 us; speedup vs baseline: 3.0626x; 1.0945x over previous
//
#include <hip/hip_runtime.h>
#include <hip/hip_bf16.h>
#include <math.h>

#define NB 32
#define NNODE 64
#define DD 128
#define NSQ 4096
#define EDGES 16384
#define LAYERS 6

typedef __bf16 bf16x8 __attribute__((ext_vector_type(8)));
typedef float f32x4 __attribute__((ext_vector_type(4)));

__device__ __forceinline__ float silu_f(float x){ return x / (1.f + __expf(-x)); }
__device__ __forceinline__ float bf2f(unsigned short h){
  union{unsigned int u; float f;} x; x.u = ((unsigned int)h)<<16; return x.f;
}

// ---------------- time embedding ----------------
__global__ void k_temb(const float* __restrict__ t, const float* __restrict__ W1,
                       const float* __restrict__ b1, const float* __restrict__ W2,
                       const float* __restrict__ b2, float* __restrict__ tt){
  int b = blockIdx.x, d = threadIdx.x;
  __shared__ float h[DD];
  float v = t[b]*W1[d] + b1[d];
  h[d] = silu_f(v);
  __syncthreads();
  float acc = b2[d];
  #pragma unroll 4
  for (int k=0;k<DD;k++) acc = fmaf(h[k], W2[k*DD+d], acc);
  tt[b*DD+d] = silu_f(acc);
}

// ---------------- edge-type table (16 types) ----------------
__global__ void k_edgeenc(const float* __restrict__ emb, const float* __restrict__ W1,
                          const float* __restrict__ b1, const float* __restrict__ W2,
                          const float* __restrict__ b2, float* __restrict__ enc){
  int et = blockIdx.x, tid = threadIdx.x;
  __shared__ float e0[DD];
  __shared__ float hid[2*DD];
  if (tid < DD) e0[tid] = emb[et*DD + tid];
  __syncthreads();
  float a = b1[tid];
  for (int d2=0; d2<DD; d2++) a = fmaf(e0[d2], W1[d2*256 + tid], a);
  hid[tid] = fmaxf(a, 0.f);
  __syncthreads();
  if (tid < DD){
    float o = b2[tid];
    for (int k=0;k<256;k++) o = fmaf(hid[k], W2[k*DD + tid], o);
    enc[et*DD + tid] = o;
  }
}

// ---------------- histogram scatter: 1 atomic per edge ----------------
__global__ void k_cnt(const int* __restrict__ ei, const int* __restrict__ attr,
                      unsigned int* __restrict__ cnt, int b0){
  int e = b0*512 + blockIdx.x*256 + threadIdx.x;
  int s = ei[e], dN = ei[EDGES+e];
  int g = (s>>6) - b0, u = s&63, v = dN&63;
  atomicAdd(&cnt[((size_t)g*4096 + v*64 + u)*16 + attr[e]], 1u);
}

// ---------------- expand: A_S[d][cell] = tt[g][d] * sum_et cnt[cell][et]*enc[et][d] ----------------
__global__ __launch_bounds__(256) void k_expand(const unsigned int* __restrict__ cnt,
    const float* __restrict__ enc, const float* __restrict__ tt,
    __bf16* __restrict__ A_S, int b0){
  __shared__ float encs[16][128];
  __shared__ float ttl[128];
  __shared__ __bf16 tb[8][256];
  int g = blockIdx.x >> 4;
  int cell0 = (blockIdx.x & 15) << 8;
  int tid = threadIdx.x;
  for (int s = tid; s < 2048; s += 256) encs[s>>7][s&127] = enc[s];
  if (tid < 128) ttl[tid] = tt[(b0+g)*128 + tid];
  unsigned int c16[16];
  { const uint4* src = (const uint4*)(cnt + ((size_t)g*4096 + cell0 + tid)*16);
    uint4 a = src[0], b = src[1], c = src[2], d = src[3];
    c16[0]=a.x; c16[1]=a.y; c16[2]=a.z; c16[3]=a.w;
    c16[4]=b.x; c16[5]=b.y; c16[6]=b.z; c16[7]=b.w;
    c16[8]=c.x; c16[9]=c.y; c16[10]=c.z; c16[11]=c.w;
    c16[12]=d.x; c16[13]=d.y; c16[14]=d.z; c16[15]=d.w; }
  __syncthreads();
  for (int dc=0; dc<16; dc++){
    int d0 = dc*8;
    float vals[8] = {0.f,0.f,0.f,0.f,0.f,0.f,0.f,0.f};
    #pragma unroll
    for (int et=0; et<16; et++){
      unsigned int c = c16[et];
      if (c){
        float fc = (float)c;
        #pragma unroll
        for (int dd=0; dd<8; dd++) vals[dd] = fmaf(fc, encs[et][d0+dd], vals[dd]);
      }
    }
    #pragma unroll
    for (int dd=0; dd<8; dd++) tb[dd][tid] = (__bf16)(vals[dd]*ttl[d0+dd]);
    __syncthreads();
    { int dd = tid>>5, seg = tid&31;
      uint4 v = *(const uint4*)&tb[dd][seg*8];
      *(uint4*)(A_S + ((size_t)(g*128 + d0 + dd)<<12) + cell0 + seg*8) = v; }
    __syncthreads();
  }
}

// ---------------- weight prep: Wt[fo][K] = W^T in bf16 ----------------
__global__ __launch_bounds__(256) void k_wprep(const float* __restrict__ W1, const float* __restrict__ W2,
                                               const float* __restrict__ Wm, __bf16* __restrict__ WT){
  int b = blockIdx.x, t = threadIdx.x;
  const float* src; __bf16* dst; int K;
  if (b < 6){ src = W1 + (size_t)b*384*128; dst = WT + (size_t)b*49152; K = 384; }
  else if (b < 12){ src = W2 + (size_t)(b-6)*128*128; dst = WT + 294912 + (size_t)(b-6)*16384; K = 128; }
  else { src = Wm; dst = WT + 393216; K = 128; }
  __shared__ float L[64][129];
  for (int k0 = 0; k0 < K; k0 += 64){
    __syncthreads();
    int r = t>>2, c = (t&3)*32;
    #pragma unroll
    for (int e=0;e<32;e+=4){
      float4 x = *(const float4*)(src + (size_t)(k0+r)*128 + c + e);
      L[r][c+e]=x.x; L[r][c+e+1]=x.y; L[r][c+e+2]=x.z; L[r][c+e+3]=x.w;
    }
    __syncthreads();
    int fo = t>>1, kk = (t&1)*32;
    union { __bf16 h[32]; uint4 u[4]; } o;
    #pragma unroll
    for (int e=0;e<32;e++) o.h[e] = (__bf16)L[kk+e][fo];
    uint4* d4 = (uint4*)(dst + (size_t)fo*K + k0 + kk);
    d4[0]=o.u[0]; d4[1]=o.u[1]; d4[2]=o.u[2]; d4[3]=o.u[3];
  }
}

// ---------------- fn weights -> bf16 (no transpose) ----------------
__global__ void k_w2bf(const float* __restrict__ W1, const float* __restrict__ W2,
                       __bf16* __restrict__ o1, __bf16* __restrict__ o2){
  int i = blockIdx.x*256 + threadIdx.x;
  o1[i] = (__bf16)W1[i];
  o2[i] = (__bf16)W2[i];
}

// ---------------- einsum (MFMA): stages A_S,X_S; derives A_N,X_N in LDS ----------------
__global__ __launch_bounds__(256) void k_einsum(const __bf16* __restrict__ As,
                                                const __bf16* __restrict__ Xs,
                                                __bf16* __restrict__ X1t, __bf16* __restrict__ X2t){
  __shared__ __bf16 S[8][4096];
  int tid = threadIdx.x;
  size_t p0 = (size_t)blockIdx.x * 2;
  // stage: A_S -> S[2],S[3]; X_S -> S[6],S[7]
  #pragma unroll
  for (int k2 = 0; k2 < 4; k2++){
    int slot = (k2 < 2) ? (2 + k2) : (4 + k2);
    const __bf16* srcp = (k2 < 2) ? As : Xs;
    const uint4* g = (const uint4*)(srcp + (p0 + (k2&1))*4096);
    #pragma unroll
    for (int s = 0; s < 2; s++){
      int idx = tid + s*256;
      uint4 v = g[idx];
      int row = idx>>3, slt = idx&7;
      *(uint4*)&S[slot][row*64 + ((slt ^ (row&7))<<3)] = v;
    }
  }
  __syncthreads();
  // derive transposes: S[0]=T(S[2]) S[1]=T(S[3]) S[4]=T(S[6]) S[5]=T(S[7])
  {
    int q = tid>>6, v = tid&63;
    int ssl = (q<2) ? (2+q) : (4+q);
    int dsl = (q<2) ? q : (2+q);
    const unsigned char* sb = (const unsigned char*)S[ssl];
    unsigned char* db = (unsigned char*)S[dsl];
    #pragma unroll
    for (int uo=0; uo<8; uo++){
      union { __bf16 h[8]; uint4 u; } pk;
      #pragma unroll
      for (int e=0;e<8;e++){
        int u = uo*8+e;
        pk.h[e] = *(const __bf16*)(sb + u*128 + (((v>>3) ^ (u&7))<<4) + (v&7)*2);
      }
      *(uint4*)(db + v*128 + ((uo ^ (v&7))<<4)) = pk.u;
    }
  }
  __syncthreads();
  int w = tid>>6, lane = tid&63;
  int pl = w>>1, pr = w&1;
  const __bf16* M  = pr ? S[4+pl] : S[0+pl];
  const __bf16* Bt = pr ? S[2+pl] : S[6+pl];
  f32x4 acc[4][4];
  #pragma unroll
  for (int a=0;a<4;a++)
    #pragma unroll
    for(int b=0;b<4;b++) acc[a][b] = (f32x4){0.f,0.f,0.f,0.f};
  int lr = lane&15, lq = lane>>4;
  #pragma unroll
  for (int ks=0;ks<2;ks++){
    bf16x8 af[4], bfr[4];
    #pragma unroll
    for (int mt=0;mt<4;mt++){ int r = mt*16+lr; af[mt] = *(const bf16x8*)&M[r*64 + (((ks*4+lq) ^ (r&7))<<3)]; }
    #pragma unroll
    for (int nt=0;nt<4;nt++){ int r = nt*16+lr; bfr[nt] = *(const bf16x8*)&Bt[r*64 + (((ks*4+lq) ^ (r&7))<<3)]; }
    #pragma unroll
    for (int mt=0;mt<4;mt++)
      #pragma unroll
      for (int nt=0;nt<4;nt++)
        acc[mt][nt] = __builtin_amdgcn_mfma_f32_16x16x32_bf16(af[mt], bfr[nt], acc[mt][nt], 0,0,0);
  }
  __bf16* OUT = (pr ? X2t : X1t) + (p0+pl)*4096;
  #pragma unroll
  for (int mt=0;mt<4;mt++)
    #pragma unroll
    for (int nt=0;nt<4;nt++){
      int col = nt*16 + lr; int row0 = mt*16 + lq*4;
      union { __bf16 h[4]; uint2 u; } o;
      #pragma unroll
      for (int r=0;r<4;r++) o.h[r] = (__bf16)acc[mt][nt][r];
      *(uint2*)&OUT[col*64 + row0] = o.u;
    }
}

// ---------------- fused conv1+LN1+relu+conv2+LN2+relu+residual (conflict-free staging) ----------------
__global__ __launch_bounds__(256) void k_layer(const __bf16* __restrict__ Xold,
    const __bf16* __restrict__ X1, const __bf16* __restrict__ X2,
    const __bf16* __restrict__ W1t, const __bf16* __restrict__ W2t,
    const float* __restrict__ b1v, const float* __restrict__ g1v, const float* __restrict__ bt1v,
    const float* __restrict__ b2v, const float* __restrict__ g2v, const float* __restrict__ bt2v,
    __bf16* __restrict__ Xnew){
  __shared__ __align__(16) unsigned char WcB[8192];
  __shared__ __align__(16) unsigned char RG[32768];   // GEMM1: Nc(8K)+Cc(8K); GEMM2: y1T(32K)
  __shared__ float redS[4][128], redQ[4][128];
  __shared__ float stats[2][128];
  __bf16* Wc = (__bf16*)WcB;
  unsigned char* Nc = RG;
  unsigned char* Cc = RG + 8192;
  __bf16* y1T = (__bf16*)RG;
  int tid = threadIdx.x, w = tid>>6, lane = tid&63, lr = lane&15, lq = lane>>4;
  int colTile = blockIdx.x << 7;
  int bl = colTile >> 12;
  int colInB = colTile & 4095;
  f32x4 acc[2][8];
  #pragma unroll
  for (int a=0;a<2;a++)
    #pragma unroll
    for (int b=0;b<8;b++) acc[a][b] = (f32x4){0.f,0.f,0.f,0.f};

  // ---- GEMM1: K=384 ----
  for (int ks=0; ks<12; ks++){
    __syncthreads();
    { // stage Wt slice [128 fo][32 k]
      int fo = tid>>1, half = tid&1;
      const uint4* src = (const uint4*)(W1t + (size_t)fo*384 + ks*32 + half*16);
      uint4 v0 = src[0], v1 = src[1];
      *(uint4*)&Wc[fo*32 + (((half*2+0) ^ (fo&3))<<3)] = v0;
      *(uint4*)&Wc[fo*32 + (((half*2+1) ^ (fo&3))<<3)] = v1;
    }
    { // p1: native slice [32 fi][128 col]
      int fi = tid>>3, o = tid&7;
      int gfi = ks*32 + fi;
      const __bf16* T = (gfi<128)? Xold : (gfi<256? X1 : X2);
      int d = gfi & 127;
      const uint4* src = (const uint4*)(T + ((size_t)(bl*128 + d)<<12) + colInB + o*16);
      uint4 v0 = src[0], v1 = src[1];
      *(uint4*)(Nc + fi*256 + (((o*2+0) ^ (fi&15))<<4)) = v0;
      *(uint4*)(Nc + fi*256 + (((o*2+1) ^ (fi&15))<<4)) = v1;
    }
    __syncthreads();
    { // p2: gather-transpose Nc -> Cc[128 col][32 fi]
      int col = tid>>1;
      #pragma unroll
      for (int j=0;j<2;j++){
        int oct = (tid&1)*2 + j;
        union { __bf16 h[8]; uint4 u; } pk;
        #pragma unroll
        for (int e=0;e<8;e++){
          int fi = oct*8 + e;
          pk.h[e] = *(const __bf16*)(Nc + fi*256 + (((col>>3) ^ (fi&15))<<4) + (col&7)*2);
        }
        *(uint4*)(Cc + col*64 + ((oct ^ (col&3))<<4)) = pk.u;
      }
    }
    __syncthreads();
    bf16x8 af[2], bfr[8];
    #pragma unroll
    for (int mt=0;mt<2;mt++){ int fo = w*32+mt*16+lr; af[mt] = *(const bf16x8*)&Wc[fo*32 + ((lq ^ (fo&3))<<3)]; }
    #pragma unroll
    for (int nt=0;nt<8;nt++){ int cr = nt*16+lr; bfr[nt] = *(const bf16x8*)(Cc + cr*64 + ((lq ^ (cr&3))<<4)); }
    #pragma unroll
    for (int mt=0;mt<2;mt++)
      #pragma unroll
      for (int nt=0;nt<8;nt++)
        acc[mt][nt] = __builtin_amdgcn_mfma_f32_16x16x32_bf16(af[mt], bfr[nt], acc[mt][nt], 0,0,0);
  }

  // ---- bias1 + LN1 ----
  #pragma unroll
  for (int mt=0;mt<2;mt++){
    #pragma unroll
    for (int r=0;r<4;r++){
      float bv = b1v[w*32 + mt*16 + lq*4 + r];
      #pragma unroll
      for (int nt=0;nt<8;nt++) acc[mt][nt][r] += bv;
    }
  }
  {
    float cs[8], cq[8];
    #pragma unroll
    for (int nt=0;nt<8;nt++){ cs[nt]=0.f; cq[nt]=0.f; }
    #pragma unroll
    for (int mt=0;mt<2;mt++)
      #pragma unroll
      for (int nt=0;nt<8;nt++)
        #pragma unroll
        for (int r=0;r<4;r++){ float v = acc[mt][nt][r]; cs[nt] += v; cq[nt] = fmaf(v,v,cq[nt]); }
    #pragma unroll
    for (int nt=0;nt<8;nt++){
      cs[nt] += __shfl_xor(cs[nt], 16); cq[nt] += __shfl_xor(cq[nt], 16);
      cs[nt] += __shfl_xor(cs[nt], 32); cq[nt] += __shfl_xor(cq[nt], 32);
    }
    if (lq == 0){
      #pragma unroll
      for (int nt=0;nt<8;nt++){ redS[w][nt*16+lr] = cs[nt]; redQ[w][nt*16+lr] = cq[nt]; }
    }
  }
  __syncthreads();
  if (tid < 128){
    float S = redS[0][tid]+redS[1][tid]+redS[2][tid]+redS[3][tid];
    float Q = redQ[0][tid]+redQ[1][tid]+redQ[2][tid]+redQ[3][tid];
    float m = S*(1.f/128.f);
    float var = Q*(1.f/128.f) - m*m;
    stats[0][tid] = m; stats[1][tid] = rsqrtf(var + 1e-5f);
  }
  __syncthreads();
  // ---- LN1 apply + relu -> y1T (overwrites Nc/Cc region; all reads done) ----
  #pragma unroll
  for (int mt=0;mt<2;mt++){
    int fo1b = w*32 + mt*16 + lq*4;
    float ga[4], be[4];
    #pragma unroll
    for (int r=0;r<4;r++){ ga[r] = g1v[fo1b+r]; be[r] = bt1v[fo1b+r]; }
    #pragma unroll
    for (int nt=0;nt<8;nt++){
      int col = nt*16 + lr;
      union { __bf16 h[4]; uint2 u; } o;
      #pragma unroll
      for (int r=0;r<4;r++){
        float xx = (acc[mt][nt][r] - stats[0][col]) * stats[1][col] * ga[r] + be[r];
        o.h[r] = (__bf16)fmaxf(xx, 0.f);
      }
      *(uint2*)&y1T[col*128 + (fo1b ^ ((col&15)<<3))] = o.u;
    }
  }
  __syncthreads();

  // ---- GEMM2: K=128 from y1T ----
  f32x4 acc2[2][8];
  #pragma unroll
  for (int a=0;a<2;a++)
    #pragma unroll
    for (int b=0;b<8;b++) acc2[a][b] = (f32x4){0.f,0.f,0.f,0.f};
  for (int ks2=0; ks2<4; ks2++){
    if (ks2) __syncthreads();
    { int fo = tid>>1, half = tid&1;
      const uint4* src = (const uint4*)(W2t + (size_t)fo*128 + ks2*32 + half*16);
      uint4 v0 = src[0], v1 = src[1];
      *(uint4*)&Wc[fo*32 + (((half*2+0) ^ (fo&3))<<3)] = v0;
      *(uint4*)&Wc[fo*32 + (((half*2+1) ^ (fo&3))<<3)] = v1;
    }
    __syncthreads();
    bf16x8 af[2], bfr[8];
    #pragma unroll
    for (int mt=0;mt<2;mt++){ int fo = w*32+mt*16+lr; af[mt] = *(const bf16x8*)&Wc[fo*32 + ((lq ^ (fo&3))<<3)]; }
    #pragma unroll
    for (int nt=0;nt<8;nt++){ int cr = nt*16+lr; bfr[nt] = *(const bf16x8*)&y1T[cr*128 + ((ks2*32 + lq*8) ^ ((cr&15)<<3))]; }
    #pragma unroll
    for (int mt=0;mt<2;mt++)
      #pragma unroll
      for (int nt=0;nt<8;nt++)
        acc2[mt][nt] = __builtin_amdgcn_mfma_f32_16x16x32_bf16(af[mt], bfr[nt], acc2[mt][nt], 0,0,0);
  }

  // ---- bias2 + LN2 ----
  #pragma unroll
  for (int mt=0;mt<2;mt++){
    #pragma unroll
    for (int r=0;r<4;r++){
      float bv = b2v[w*32 + mt*16 + lq*4 + r];
      #pragma unroll
      for (int nt=0;nt<8;nt++) acc2[mt][nt][r] += bv;
    }
  }
  {
    float cs[8], cq[8];
    #pragma unroll
    for (int nt=0;nt<8;nt++){ cs[nt]=0.f; cq[nt]=0.f; }
    #pragma unroll
    for (int mt=0;mt<2;mt++)
      #pragma unroll
      for (int nt=0;nt<8;nt++)
        #pragma unroll
        for (int r=0;r<4;r++){ float v = acc2[mt][nt][r]; cs[nt] += v; cq[nt] = fmaf(v,v,cq[nt]); }
    #pragma unroll
    for (int nt=0;nt<8;nt++){
      cs[nt] += __shfl_xor(cs[nt], 16); cq[nt] += __shfl_xor(cq[nt], 16);
      cs[nt] += __shfl_xor(cs[nt], 32); cq[nt] += __shfl_xor(cq[nt], 32);
    }
    if (lq == 0){
      #pragma unroll
      for (int nt=0;nt<8;nt++){ redS[w][nt*16+lr] = cs[nt]; redQ[w][nt*16+lr] = cq[nt]; }
    }
  }
  __syncthreads();
  if (tid < 128){
    float S = redS[0][tid]+redS[1][tid]+redS[2][tid]+redS[3][tid];
    float Q = redQ[0][tid]+redQ[1][tid]+redQ[2][tid]+redQ[3][tid];
    float m = S*(1.f/128.f);
    float var = Q*(1.f/128.f) - m*m;
    stats[0][tid] = m; stats[1][tid] = rsqrtf(var + 1e-5f);
  }
  __syncthreads();
  // ---- LN2 apply + relu + residual -> Xnew ----
  #pragma unroll
  for (int mt=0;mt<2;mt++){
    #pragma unroll
    for (int r=0;r<4;r++){
      int fo = w*32 + mt*16 + lq*4 + r;
      float ga = g2v[fo], be = bt2v[fo];
      size_t rowb = ((size_t)(bl*128 + fo)<<12) + colInB;
      #pragma unroll
      for (int nt=0;nt<8;nt++){
        int cp = nt*16 + lr;
        float xx = (acc2[mt][nt][r] - stats[0][cp]) * stats[1][cp] * ga + be;
        float o = fmaxf(xx, 0.f);
        float old = (float)Xold[rowb + cp];
        Xnew[rowb + cp] = (__bf16)(o + old);
      }
    }
  }
}

// ---------------- symmetrize: out = in + in^T (per plane, bf16) ----------------
__global__ __launch_bounds__(256) void k_sym(const __bf16* __restrict__ Xin, __bf16* __restrict__ Xout){
  __shared__ float P[64][65];
  size_t base = (size_t)blockIdx.x * 4096;
  int tid = threadIdx.x;
  int f = tid*16, r = f>>6, c = f&63;
  union { __bf16 h[16]; uint4 u[2]; } in;
  in.u[0] = *(const uint4*)(Xin + base + f);
  in.u[1] = *(const uint4*)(Xin + base + f + 8);
  #pragma unroll
  for (int e=0;e<16;e++) P[r][c+e] = (float)in.h[e];
  __syncthreads();
  union { __bf16 h[16]; uint4 u[2]; } o;
  #pragma unroll
  for (int e=0;e<16;e++) o.h[e] = (__bf16)(P[r][c+e] + P[c+e][r]);
  *(uint4*)(Xout + base + f)     = o.u[0];
  *(uint4*)(Xout + base + f + 8) = o.u[1];
}

// ---------------- to node-major: NM[g*4096+cell][d] = S[g*128+d][cell] ----------------
__global__ __launch_bounds__(256) void k_tonm(const __bf16* __restrict__ S, __bf16* __restrict__ NM){
  __shared__ unsigned short L[64][65];
  int b = blockIdx.x;
  int g = b >> 7, dh = (b>>6)&1, cc = b&63;
  int cell0 = cc*64, d0 = dh*64;
  int tid = threadIdx.x;
  int r = tid>>2, c = (tid&3)*16;
  union { unsigned short h[16]; uint4 u[2]; } in;
  const unsigned short* src = (const unsigned short*)S + ((size_t)(g*128 + d0 + r)<<12) + cell0 + c;
  in.u[0] = *(const uint4*)src;
  in.u[1] = *(const uint4*)(src + 8);
  #pragma unroll
  for (int e=0;e<16;e++) L[r][c+e] = in.h[e];
  __syncthreads();
  union { unsigned short h[16]; uint4 u[2]; } o;
  int cr = tid>>2, dc = (tid&3)*16;
  #pragma unroll
  for (int e=0;e<16;e++) o.h[e] = L[dc+e][cr];
  unsigned short* dst = (unsigned short*)NM + (size_t)(g*4096 + cell0 + cr)*128 + d0 + dc;
  *(uint4*)dst       = o.u[0];
  *(uint4*)(dst + 8) = o.u[1];
}

// ---------------- mlp hidden from cell-major: hid[cell][fo] = silu(NM[cell][:]@W1m + b) ----------------
__global__ __launch_bounds__(256) void k_mlph(const __bf16* __restrict__ NM,
    const __bf16* __restrict__ Wt, const float* __restrict__ bias, __bf16* __restrict__ hid){
  __shared__ __align__(16) unsigned char WcB[8192];
  __shared__ __align__(16) unsigned char EcB[8192];
  __bf16* Wc = (__bf16*)WcB;
  unsigned char* Ec = EcB;
  int tid = threadIdx.x, w = tid>>6, lane = tid&63, lr = lane&15, lq = lane>>4;
  int g = blockIdx.x >> 5;
  size_t cellbase = ((size_t)g<<12) + ((size_t)(blockIdx.x & 31) << 7);
  int mh = w&1, nh = w>>1;
  f32x4 acc[4][4];
  #pragma unroll
  for (int a=0;a<4;a++)
    #pragma unroll
    for (int b=0;b<4;b++) acc[a][b] = (f32x4){0.f,0.f,0.f,0.f};
  for (int ks=0; ks<4; ks++){
    __syncthreads();
    { int fo = tid>>1, half = tid&1;
      const uint4* src = (const uint4*)(Wt + (size_t)fo*128 + ks*32 + half*16);
      uint4 v0 = src[0], v1 = src[1];
      *(uint4*)&Wc[fo*32 + (((half*2+0) ^ (fo&3))<<3)] = v0;
      *(uint4*)&Wc[fo*32 + (((half*2+1) ^ (fo&3))<<3)] = v1;
    }
    { int cell = tid>>1, half = tid&1;
      const uint4* src = (const uint4*)(NM + (cellbase + cell)*128 + ks*32 + half*16);
      uint4 v0 = src[0], v1 = src[1];
      *(uint4*)(Ec + cell*64 + (((half*2+0) ^ (cell&3))<<4)) = v0;
      *(uint4*)(Ec + cell*64 + (((half*2+1) ^ (cell&3))<<4)) = v1;
    }
    __syncthreads();
    bf16x8 af[4], bfr[4];
    #pragma unroll
    for (int mt=0;mt<4;mt++){ int cr = mh*64 + mt*16 + lr; af[mt] = *(const bf16x8*)(Ec + cr*64 + ((lq ^ (cr&3))<<4)); }
    #pragma unroll
    for (int nt=0;nt<4;nt++){ int fo = nh*64 + nt*16 + lr; bfr[nt] = *(const bf16x8*)&Wc[fo*32 + ((lq ^ (fo&3))<<3)]; }
    #pragma unroll
    for (int mt=0;mt<4;mt++)
      #pragma unroll
      for (int nt=0;nt<4;nt++)
        acc[mt][nt] = __builtin_amdgcn_mfma_f32_16x16x32_bf16(af[mt], bfr[nt], acc[mt][nt], 0,0,0);
  }
  #pragma unroll
  for (int mt=0;mt<4;mt++)
    #pragma unroll
    for (int r=0;r<4;r++){
      size_t cell = cellbase + mh*64 + mt*16 + lq*4 + r;
      #pragma unroll
      for (int nt=0;nt<4;nt++){
        int fo = nh*64 + nt*16 + lr;
        hid[cell*128 + fo] = (__bf16)silu_f(acc[mt][nt][r] + bias[fo]);
      }
    }
}

// ---------------- ym[(g,i)][fo] = mean over v of hid[v*64+i][fo] ----------------
__global__ void k_ymean(const __bf16* __restrict__ hid, float* __restrict__ ym){
  __shared__ float red[256];
  int g = blockIdx.x >> 6, u = blockIdx.x & 63;
  int fo = threadIdx.x & 127, vh = threadIdx.x >> 7;
  const unsigned short* hu = (const unsigned short*)hid;
  float s = 0.f;
  for (int v = vh; v < 64; v += 2)
    s += bf2f(hu[((size_t)g*4096 + v*64 + u)*128 + fo]);
  red[threadIdx.x] = s;
  __syncthreads();
  if (vh == 0) ym[((size_t)g*64 + u)*128 + fo] = (red[fo] + red[128+fo]) * (1.f/64.f);
}

// ---------------- h2 = ym @ mlp_W2 + b2 ----------------
__global__ void k_h2(const float* __restrict__ ym, const float* __restrict__ W2,
                     const float* __restrict__ b2, float* __restrict__ h2){
  int row = blockIdx.x, fo = threadIdx.x;
  __shared__ float rr[128];
  rr[fo] = ym[(size_t)row*128 + fo];
  __syncthreads();
  float a = b2[fo];
  #pragma unroll 4
  for (int k=0;k<128;k++) a = fmaf(rr[k], W2[k*128+fo], a);
  h2[(size_t)row*128+fo] = a;
}

// ---------------- final MLP for edges (32 edges/block, bf16 weights) ----------------
__global__ __launch_bounds__(256) void k_fedge(const __bf16* __restrict__ NM, const int* __restrict__ ei,
    const __bf16* __restrict__ W1, const float* __restrict__ b1,
    const __bf16* __restrict__ W2, const float* __restrict__ b2, float* __restrict__ outp, int b0){
  __shared__ float eo[32][128];
  __shared__ float hid[32][264];
  __shared__ int cells[32];
  int tid = threadIdx.x;
  int e0 = b0*512 + blockIdx.x*32;
  if (tid < 32){
    int e = e0 + tid;
    int s = ei[e], dN = ei[EDGES + e];
    cells[tid] = ((s>>6) - b0)*4096 + (dN&63)*64 + (s&63);
  }
  __syncthreads();
  { int el = tid>>3, d0 = (tid&7)*16;
    const unsigned short* src = (const unsigned short*)NM + (size_t)cells[el]*128 + d0;
    union { unsigned short h[16]; uint4 u[2]; } v;
    v.u[0] = *(const uint4*)src; v.u[1] = *(const uint4*)(src + 8);
    #pragma unroll
    for (int e2=0;e2<16;e2++) eo[el][d0+e2] = bf2f(v.h[e2]);
  }
  __syncthreads();
  const unsigned short* W1u = (const unsigned short*)W1;
  const unsigned short* W2u = (const unsigned short*)W2;
  float h[32];
  { float bb = b1[tid];
    #pragma unroll
    for (int e2=0;e2<32;e2++) h[e2] = bb; }
  for (int d2=0; d2<128; d2++){
    float wv = bf2f(W1u[d2*256 + tid]);
    #pragma unroll
    for (int e2=0;e2<32;e2++) h[e2] = fmaf(eo[e2][d2], wv, h[e2]);
  }
  #pragma unroll
  for (int e2=0;e2<32;e2++) hid[e2][tid] = fmaxf(h[e2], 0.f);
  __syncthreads();
  int el = tid>>3, oct = tid&7;
  float o[16];
  #pragma unroll
  for (int i=0;i<16;i++) o[i] = b2[oct*16+i];
  for (int k=0;k<256;k++){
    float hv = hid[el][k];
    union { unsigned short h[16]; uint4 u[2]; } wv;
    wv.u[0] = *(const uint4*)(W2u + k*128 + oct*16);
    wv.u[1] = *(const uint4*)(W2u + k*128 + oct*16 + 8);
    #pragma unroll
    for (int i=0;i<16;i++) o[i] = fmaf(hv, bf2f(wv.h[i]), o[i]);
  }
  float* dst = outp + (size_t)(e0 + el)*128 + oct*16;
  #pragma unroll
  for (int i=0;i<4;i++)
    *(float4*)(dst + i*4) = make_float4(o[i*4], o[i*4+1], o[i*4+2], o[i*4+3]);
}

// ---------------- final MLP for nodes (32 rows/block) ----------------
__global__ __launch_bounds__(256) void k_fnode(const float* __restrict__ h2,
    const __bf16* __restrict__ W1, const float* __restrict__ b1,
    const __bf16* __restrict__ W2, const float* __restrict__ b2, float* __restrict__ outp){
  __shared__ float eo[32][128];
  __shared__ float hid[32][264];
  int tid = threadIdx.x;
  int r0 = blockIdx.x*32;
  { int el = tid>>3, d0 = (tid&7)*16;
    const float4* src = (const float4*)(h2 + (size_t)(r0+el)*128 + d0);
    #pragma unroll
    for (int q=0;q<4;q++){
      float4 v = src[q];
      eo[el][d0+q*4+0]=v.x; eo[el][d0+q*4+1]=v.y; eo[el][d0+q*4+2]=v.z; eo[el][d0+q*4+3]=v.w;
    }
  }
  __syncthreads();
  const unsigned short* W1u = (const unsigned short*)W1;
  const unsigned short* W2u = (const unsigned short*)W2;
  float h[32];
  { float bb = b1[tid];
    #pragma unroll
    for (int e2=0;e2<32;e2++) h[e2] = bb; }
  for (int d2=0; d2<128; d2++){
    float wv = bf2f(W1u[d2*256 + tid]);
    #pragma unroll
    for (int e2=0;e2<32;e2++) h[e2] = fmaf(eo[e2][d2], wv, h[e2]);
  }
  #pragma unroll
  for (int e2=0;e2<32;e2++) hid[e2][tid] = fmaxf(h[e2], 0.f);
  __syncthreads();
  int el = tid>>3, oct = tid&7;
  float o[16];
  #pragma unroll
  for (int i=0;i<16;i++) o[i] = b2[oct*16+i];
  for (int k=0;k<256;k++){
    float hv = hid[el][k];
    union { unsigned short h[16]; uint4 u[2]; } wv;
    wv.u[0] = *(const uint4*)(W2u + k*128 + oct*16);
    wv.u[1] = *(const uint4*)(W2u + k*128 + oct*16 + 8);
    #pragma unroll
    for (int i=0;i<16;i++) o[i] = fmaf(hv, bf2f(wv.h[i]), o[i]);
  }
  float* dst = outp + (size_t)(r0 + el)*128 + oct*16;
  #pragma unroll
  for (int i=0;i<4;i++)
    *(float4*)(dst + i*4) = make_float4(o[i*4], o[i*4+1], o[i*4+2], o[i*4+3]);
}

// ---------------- graph_attr ----------------
__global__ void k_graph(const float* __restrict__ node_out, float* __restrict__ gout){
  int b = blockIdx.x, d = threadIdx.x;
  float s = 0.f;
  for (int i=0;i<64;i++) s += node_out[(size_t)(b*64+i)*128 + d];
  gout[b*128 + d] = s * (1.f/64.f);
}

extern "C" void kernel_launch(void* const* d_in, const int* in_sizes, int n_in,
                              void* d_out, int out_size, void* d_ws, size_t ws_size,
                              hipStream_t stream) {
  const int*   edge_index = (const int*)d_in[1];
  const int*   edge_attr  = (const int*)d_in[2];
  const float* t        = (const float*)d_in[3];
  const float* edge_emb = (const float*)d_in[5];
  const float* temb_W1  = (const float*)d_in[6];
  const float* temb_b1  = (const float*)d_in[7];
  const float* temb_W2  = (const float*)d_in[8];
  const float* temb_b2  = (const float*)d_in[9];
  const float* ein_W1   = (const float*)d_in[14];
  const float* ein_b1   = (const float*)d_in[15];
  const float* ein_W2   = (const float*)d_in[16];
  const float* ein_b2   = (const float*)d_in[17];
  const float* conv_W1  = (const float*)d_in[18];
  const float* conv_b1  = (const float*)d_in[19];
  const float* conv_g1  = (const float*)d_in[20];
  const float* conv_bt1 = (const float*)d_in[21];
  const float* conv_W2  = (const float*)d_in[22];
  const float* conv_b2  = (const float*)d_in[23];
  const float* conv_g2  = (const float*)d_in[24];
  const float* conv_bt2 = (const float*)d_in[25];
  const float* mlp_W1   = (const float*)d_in[26];
  const float* mlp_b1   = (const float*)d_in[27];
  const float* mlp_W2   = (const float*)d_in[28];
  const float* mlp_b2   = (const float*)d_in[29];
  const float* fn_W1    = (const float*)d_in[30];
  const float* fn_b1    = (const float*)d_in[31];
  const float* fn_W2    = (const float*)d_in[32];
  const float* fn_b2    = (const float*)d_in[33];

  float* ws  = (float*)d_ws;
  float* tt  = ws;                      // 4096
  float* enc = ws + 4096;               // 2048
  float* ym  = ws + 6144;               // 262144
  float* h2  = ws + 268288;             // 262144
  __bf16* WT = (__bf16*)(ws + 530432);  // 475136 bf16 (= 237568 f32)
  unsigned int* cnt = (unsigned int*)(ws + 768000);  // 2097152 u32
  const size_t HDRF = 2883584;

  __bf16* fnW1bf = WT + 409600;
  __bf16* fnW2bf = WT + 442368;

  size_t availF = ws_size / sizeof(float);
  const int cands[6] = {32, 16, 8, 4, 2, 1};
  int C = 1;
  for (int i = 0; i < 6; i++){
    if (HDRF + 4ull * (size_t)cands[i] * 262144ull <= availF){ C = cands[i]; break; }
  }
  const size_t PCB = (size_t)C * 262144;   // f32-equiv per bf16 plane tensor
  __bf16* A_S = (__bf16*)(ws + HDRF);
  __bf16* X_S = (__bf16*)(ws + HDRF + PCB);
  __bf16* X1  = (__bf16*)(ws + HDRF + 2*PCB);
  __bf16* X2  = (__bf16*)(ws + HDRF + 3*PCB);
  float* outf = (float*)d_out;

  k_temb<<<NB, DD, 0, stream>>>(t, temb_W1, temb_b1, temb_W2, temb_b2, tt);
  k_edgeenc<<<16, 256, 0, stream>>>(edge_emb, ein_W1, ein_b1, ein_W2, ein_b2, enc);
  k_wprep<<<13, 256, 0, stream>>>(conv_W1, conv_W2, mlp_W1, WT);
  k_w2bf<<<128, 256, 0, stream>>>(fn_W1, fn_W2, fnW1bf, fnW2bf);

  for (int b0 = 0; b0 < NB; b0 += C){
    hipMemsetAsync(cnt, 0, (size_t)C*4096*16*sizeof(unsigned int), stream);
    k_cnt<<<C*2, 256, 0, stream>>>(edge_index, edge_attr, cnt, b0);
    k_expand<<<C*16, 256, 0, stream>>>(cnt, enc, tt, A_S, b0);

    for (int l=0; l<LAYERS; l++){
      const __bf16* Xs_l = (l==0) ? A_S : X_S;
      k_einsum<<<C*64, 256, 0, stream>>>(A_S, Xs_l, X1, X2);
      k_layer<<<C*32, 256, 0, stream>>>(Xs_l, X1, X2,
          WT + (size_t)l*49152, WT + 294912 + (size_t)l*16384,
          conv_b1 + l*DD, conv_g1 + l*DD, conv_bt1 + l*DD,
          conv_b2 + l*DD, conv_g2 + l*DD, conv_bt2 + l*DD, X_S);
    }

    k_sym<<<C*128, 256, 0, stream>>>(X_S, X2);
    k_tonm<<<C*128, 256, 0, stream>>>(X2, X1);           // X1 = cell-major X
    k_mlph<<<C*32, 256, 0, stream>>>(X1, WT + 393216, mlp_b1, X2);  // X2 = hid cell-major
    k_ymean<<<C*64, 256, 0, stream>>>(X2, ym);
    k_h2<<<C*64, 128, 0, stream>>>(ym, mlp_W2, mlp_b2, h2);
    k_fedge<<<C*16, 256, 0, stream>>>(X1, edge_index, fnW1bf, fn_b1, fnW2bf, fn_b2, outf + 262144, b0);
    k_fnode<<<C*2, 256, 0, stream>>>(h2, fnW1bf, fn_b1, fnW2bf, fn_b2, outf + (size_t)b0*64*DD);
    k_graph<<<C, DD, 0, stream>>>(outf + (size_t)b0*64*DD, outf + 2359296 + b0*DD);
  }
}

// Round 6
// 654.104 us; speedup vs baseline: 3.5328x; 1.1535x over previous
//
#include <hip/hip_runtime.h>
#include <hip/hip_bf16.h>
#include <math.h>

#define NB 32
#define NNODE 64
#define DD 128
#define NSQ 4096
#define EDGES 16384
#define LAYERS 6

typedef __bf16 bf16x8 __attribute__((ext_vector_type(8)));
typedef float f32x4 __attribute__((ext_vector_type(4)));

__device__ __forceinline__ float silu_f(float x){ return x / (1.f + __expf(-x)); }
__device__ __forceinline__ float bf2f(unsigned short h){
  union{unsigned int u; float f;} x; x.u = ((unsigned int)h)<<16; return x.f;
}

// ---------------- time embedding ----------------
__global__ void k_temb(const float* __restrict__ t, const float* __restrict__ W1,
                       const float* __restrict__ b1, const float* __restrict__ W2,
                       const float* __restrict__ b2, float* __restrict__ tt){
  int b = blockIdx.x, d = threadIdx.x;
  __shared__ float h[DD];
  float v = t[b]*W1[d] + b1[d];
  h[d] = silu_f(v);
  __syncthreads();
  float acc = b2[d];
  #pragma unroll 4
  for (int k=0;k<DD;k++) acc = fmaf(h[k], W2[k*DD+d], acc);
  tt[b*DD+d] = silu_f(acc);
}

// ---------------- edge-type table (16 types) ----------------
__global__ void k_edgeenc(const float* __restrict__ emb, const float* __restrict__ W1,
                          const float* __restrict__ b1, const float* __restrict__ W2,
                          const float* __restrict__ b2, float* __restrict__ enc){
  int et = blockIdx.x, tid = threadIdx.x;
  __shared__ float e0[DD];
  __shared__ float hid[2*DD];
  if (tid < DD) e0[tid] = emb[et*DD + tid];
  __syncthreads();
  float a = b1[tid];
  for (int d2=0; d2<DD; d2++) a = fmaf(e0[d2], W1[d2*256 + tid], a);
  hid[tid] = fmaxf(a, 0.f);
  __syncthreads();
  if (tid < DD){
    float o = b2[tid];
    for (int k=0;k<256;k++) o = fmaf(hid[k], W2[k*DD + tid], o);
    enc[et*DD + tid] = o;
  }
}

// ---------------- histogram scatter: 1 atomic per edge ----------------
__global__ void k_cnt(const int* __restrict__ ei, const int* __restrict__ attr,
                      unsigned int* __restrict__ cnt, int b0){
  int e = b0*512 + blockIdx.x*256 + threadIdx.x;
  int s = ei[e], dN = ei[EDGES+e];
  int g = (s>>6) - b0, u = s&63, v = dN&63;
  atomicAdd(&cnt[((size_t)g*4096 + v*64 + u)*16 + attr[e]], 1u);
}

// ---------------- expand: A_S[d][cell] = tt[g][d] * sum_et cnt[cell][et]*enc[et][d] ----------------
__global__ __launch_bounds__(256) void k_expand(const unsigned int* __restrict__ cnt,
    const float* __restrict__ enc, const float* __restrict__ tt,
    __bf16* __restrict__ A_S, int b0){
  __shared__ float encs[16][128];
  __shared__ float ttl[128];
  __shared__ __bf16 tb[8][256];
  int g = blockIdx.x >> 4;
  int cell0 = (blockIdx.x & 15) << 8;
  int tid = threadIdx.x;
  for (int s = tid; s < 2048; s += 256) encs[s>>7][s&127] = enc[s];
  if (tid < 128) ttl[tid] = tt[(b0+g)*128 + tid];
  unsigned int c16[16];
  { const uint4* src = (const uint4*)(cnt + ((size_t)g*4096 + cell0 + tid)*16);
    uint4 a = src[0], b = src[1], c = src[2], d = src[3];
    c16[0]=a.x; c16[1]=a.y; c16[2]=a.z; c16[3]=a.w;
    c16[4]=b.x; c16[5]=b.y; c16[6]=b.z; c16[7]=b.w;
    c16[8]=c.x; c16[9]=c.y; c16[10]=c.z; c16[11]=c.w;
    c16[12]=d.x; c16[13]=d.y; c16[14]=d.z; c16[15]=d.w; }
  __syncthreads();
  for (int dc=0; dc<16; dc++){
    int d0 = dc*8;
    float vals[8] = {0.f,0.f,0.f,0.f,0.f,0.f,0.f,0.f};
    #pragma unroll
    for (int et=0; et<16; et++){
      unsigned int c = c16[et];
      if (c){
        float fc = (float)c;
        #pragma unroll
        for (int dd=0; dd<8; dd++) vals[dd] = fmaf(fc, encs[et][d0+dd], vals[dd]);
      }
    }
    #pragma unroll
    for (int dd=0; dd<8; dd++) tb[dd][tid] = (__bf16)(vals[dd]*ttl[d0+dd]);
    __syncthreads();
    { int dd = tid>>5, seg = tid&31;
      uint4 v = *(const uint4*)&tb[dd][seg*8];
      *(uint4*)(A_S + ((size_t)(g*128 + d0 + dd)<<12) + cell0 + seg*8) = v; }
    __syncthreads();
  }
}

// ---------------- weight prep: Wt[fo][K] = W^T in bf16 (conv + mlp weights) ----------------
__global__ __launch_bounds__(256) void k_wprep(const float* __restrict__ W1, const float* __restrict__ W2,
                                               const float* __restrict__ Wm, __bf16* __restrict__ WT){
  int b = blockIdx.x, t = threadIdx.x;
  const float* src; __bf16* dst; int K;
  if (b < 6){ src = W1 + (size_t)b*384*128; dst = WT + (size_t)b*49152; K = 384; }
  else if (b < 12){ src = W2 + (size_t)(b-6)*128*128; dst = WT + 294912 + (size_t)(b-6)*16384; K = 128; }
  else { src = Wm; dst = WT + 393216; K = 128; }
  __shared__ float L[64][129];
  for (int k0 = 0; k0 < K; k0 += 64){
    __syncthreads();
    int r = t>>2, c = (t&3)*32;
    #pragma unroll
    for (int e=0;e<32;e+=4){
      float4 x = *(const float4*)(src + (size_t)(k0+r)*128 + c + e);
      L[r][c+e]=x.x; L[r][c+e+1]=x.y; L[r][c+e+2]=x.z; L[r][c+e+3]=x.w;
    }
    __syncthreads();
    int fo = t>>1, kk = (t&1)*32;
    union { __bf16 h[32]; uint4 u[4]; } o;
    #pragma unroll
    for (int e=0;e<32;e++) o.h[e] = (__bf16)L[kk+e][fo];
    uint4* d4 = (uint4*)(dst + (size_t)fo*K + k0 + kk);
    d4[0]=o.u[0]; d4[1]=o.u[1]; d4[2]=o.u[2]; d4[3]=o.u[3];
  }
}

// ---------------- fn weight prep: transpose f32[K][N] -> bf16[N][K] ----------------
__global__ __launch_bounds__(256) void k_wprepfn(const float* __restrict__ W1, const float* __restrict__ W2,
                                                 __bf16* __restrict__ o1, __bf16* __restrict__ o2){
  int b = blockIdx.x, t = threadIdx.x;
  const float* src; __bf16* dst; int K, N, k0, n0;
  if (b < 8){ src = W1; dst = o1; K = 128; N = 256; k0 = (b>>2)*64; n0 = (b&3)*64; }
  else { int bb = b-8; src = W2; dst = o2; K = 256; N = 128; k0 = (bb>>1)*64; n0 = (bb&1)*64; }
  __shared__ float L[64][65];
  int r = t>>2, c4 = (t&3)*16;
  #pragma unroll
  for (int e=0;e<16;e+=4){
    float4 x = *(const float4*)(src + (size_t)(k0+r)*N + n0 + c4 + e);
    L[r][c4+e]=x.x; L[r][c4+e+1]=x.y; L[r][c4+e+2]=x.z; L[r][c4+e+3]=x.w;
  }
  __syncthreads();
  int n = t>>2, kc = (t&3)*16;
  union { __bf16 h[16]; uint4 u[2]; } o;
  #pragma unroll
  for (int e=0;e<16;e++) o.h[e] = (__bf16)L[kc+e][n];
  uint4* d4 = (uint4*)(dst + (size_t)(n0+n)*K + k0 + kc);
  d4[0]=o.u[0]; d4[1]=o.u[1];
}

// ---------------- einsum (MFMA): stages A_S,X_S; derives A_N,X_N in LDS ----------------
__global__ __launch_bounds__(256) void k_einsum(const __bf16* __restrict__ As,
                                                const __bf16* __restrict__ Xs,
                                                __bf16* __restrict__ X1t, __bf16* __restrict__ X2t){
  __shared__ __bf16 S[8][4096];
  int tid = threadIdx.x;
  size_t p0 = (size_t)blockIdx.x * 2;
  #pragma unroll
  for (int k2 = 0; k2 < 4; k2++){
    int slot = (k2 < 2) ? (2 + k2) : (4 + k2);
    const __bf16* srcp = (k2 < 2) ? As : Xs;
    const uint4* g = (const uint4*)(srcp + (p0 + (k2&1))*4096);
    #pragma unroll
    for (int s = 0; s < 2; s++){
      int idx = tid + s*256;
      uint4 v = g[idx];
      int row = idx>>3, slt = idx&7;
      *(uint4*)&S[slot][row*64 + ((slt ^ (row&7))<<3)] = v;
    }
  }
  __syncthreads();
  {
    int q = tid>>6, v = tid&63;
    int ssl = (q<2) ? (2+q) : (4+q);
    int dsl = (q<2) ? q : (2+q);
    const unsigned char* sb = (const unsigned char*)S[ssl];
    unsigned char* db = (unsigned char*)S[dsl];
    #pragma unroll
    for (int uo=0; uo<8; uo++){
      union { __bf16 h[8]; uint4 u; } pk;
      #pragma unroll
      for (int e=0;e<8;e++){
        int u = uo*8+e;
        pk.h[e] = *(const __bf16*)(sb + u*128 + (((v>>3) ^ (u&7))<<4) + (v&7)*2);
      }
      *(uint4*)(db + v*128 + ((uo ^ (v&7))<<4)) = pk.u;
    }
  }
  __syncthreads();
  int w = tid>>6, lane = tid&63;
  int pl = w>>1, pr = w&1;
  const __bf16* M  = pr ? S[4+pl] : S[0+pl];
  const __bf16* Bt = pr ? S[2+pl] : S[6+pl];
  f32x4 acc[4][4];
  #pragma unroll
  for (int a=0;a<4;a++)
    #pragma unroll
    for(int b=0;b<4;b++) acc[a][b] = (f32x4){0.f,0.f,0.f,0.f};
  int lr = lane&15, lq = lane>>4;
  #pragma unroll
  for (int ks=0;ks<2;ks++){
    bf16x8 af[4], bfr[4];
    #pragma unroll
    for (int mt=0;mt<4;mt++){ int r = mt*16+lr; af[mt] = *(const bf16x8*)&M[r*64 + (((ks*4+lq) ^ (r&7))<<3)]; }
    #pragma unroll
    for (int nt=0;nt<4;nt++){ int r = nt*16+lr; bfr[nt] = *(const bf16x8*)&Bt[r*64 + (((ks*4+lq) ^ (r&7))<<3)]; }
    #pragma unroll
    for (int mt=0;mt<4;mt++)
      #pragma unroll
      for (int nt=0;nt<4;nt++)
        acc[mt][nt] = __builtin_amdgcn_mfma_f32_16x16x32_bf16(af[mt], bfr[nt], acc[mt][nt], 0,0,0);
  }
  __bf16* OUT = (pr ? X2t : X1t) + (p0+pl)*4096;
  #pragma unroll
  for (int mt=0;mt<4;mt++)
    #pragma unroll
    for (int nt=0;nt<4;nt++){
      int col = nt*16 + lr; int row0 = mt*16 + lq*4;
      union { __bf16 h[4]; uint2 u; } o;
      #pragma unroll
      for (int r=0;r<4;r++) o.h[r] = (__bf16)acc[mt][nt][r];
      *(uint2*)&OUT[col*64 + row0] = o.u;
    }
}

// ---------------- fused conv1+LN1+relu+conv2+LN2+relu+residual ----------------
__global__ __launch_bounds__(256) void k_layer(const __bf16* __restrict__ Xold,
    const __bf16* __restrict__ X1, const __bf16* __restrict__ X2,
    const __bf16* __restrict__ W1t, const __bf16* __restrict__ W2t,
    const float* __restrict__ b1v, const float* __restrict__ g1v, const float* __restrict__ bt1v,
    const float* __restrict__ b2v, const float* __restrict__ g2v, const float* __restrict__ bt2v,
    __bf16* __restrict__ Xnew){
  __shared__ __align__(16) unsigned char WcB[8192];
  __shared__ __align__(16) unsigned char RG[32768];
  __shared__ float redS[4][128], redQ[4][128];
  __shared__ float stats[2][128];
  __bf16* Wc = (__bf16*)WcB;
  unsigned char* Nc = RG;
  unsigned char* Cc = RG + 8192;
  __bf16* y1T = (__bf16*)RG;
  int tid = threadIdx.x, w = tid>>6, lane = tid&63, lr = lane&15, lq = lane>>4;
  int colTile = blockIdx.x << 7;
  int bl = colTile >> 12;
  int colInB = colTile & 4095;
  f32x4 acc[2][8];
  #pragma unroll
  for (int a=0;a<2;a++)
    #pragma unroll
    for (int b=0;b<8;b++) acc[a][b] = (f32x4){0.f,0.f,0.f,0.f};

  for (int ks=0; ks<12; ks++){
    __syncthreads();
    { int fo = tid>>1, half = tid&1;
      const uint4* src = (const uint4*)(W1t + (size_t)fo*384 + ks*32 + half*16);
      uint4 v0 = src[0], v1 = src[1];
      *(uint4*)&Wc[fo*32 + (((half*2+0) ^ (fo&3))<<3)] = v0;
      *(uint4*)&Wc[fo*32 + (((half*2+1) ^ (fo&3))<<3)] = v1;
    }
    { int fi = tid>>3, o = tid&7;
      int gfi = ks*32 + fi;
      const __bf16* T = (gfi<128)? Xold : (gfi<256? X1 : X2);
      int d = gfi & 127;
      const uint4* src = (const uint4*)(T + ((size_t)(bl*128 + d)<<12) + colInB + o*16);
      uint4 v0 = src[0], v1 = src[1];
      *(uint4*)(Nc + fi*256 + (((o*2+0) ^ (fi&15))<<4)) = v0;
      *(uint4*)(Nc + fi*256 + (((o*2+1) ^ (fi&15))<<4)) = v1;
    }
    __syncthreads();
    { int col = tid>>1;
      #pragma unroll
      for (int j=0;j<2;j++){
        int oct = (tid&1)*2 + j;
        union { __bf16 h[8]; uint4 u; } pk;
        #pragma unroll
        for (int e=0;e<8;e++){
          int fi = oct*8 + e;
          pk.h[e] = *(const __bf16*)(Nc + fi*256 + (((col>>3) ^ (fi&15))<<4) + (col&7)*2);
        }
        *(uint4*)(Cc + col*64 + ((oct ^ (col&3))<<4)) = pk.u;
      }
    }
    __syncthreads();
    bf16x8 af[2], bfr[8];
    #pragma unroll
    for (int mt=0;mt<2;mt++){ int fo = w*32+mt*16+lr; af[mt] = *(const bf16x8*)&Wc[fo*32 + ((lq ^ (fo&3))<<3)]; }
    #pragma unroll
    for (int nt=0;nt<8;nt++){ int cr = nt*16+lr; bfr[nt] = *(const bf16x8*)(Cc + cr*64 + ((lq ^ (cr&3))<<4)); }
    #pragma unroll
    for (int mt=0;mt<2;mt++)
      #pragma unroll
      for (int nt=0;nt<8;nt++)
        acc[mt][nt] = __builtin_amdgcn_mfma_f32_16x16x32_bf16(af[mt], bfr[nt], acc[mt][nt], 0,0,0);
  }

  #pragma unroll
  for (int mt=0;mt<2;mt++){
    #pragma unroll
    for (int r=0;r<4;r++){
      float bv = b1v[w*32 + mt*16 + lq*4 + r];
      #pragma unroll
      for (int nt=0;nt<8;nt++) acc[mt][nt][r] += bv;
    }
  }
  {
    float cs[8], cq[8];
    #pragma unroll
    for (int nt=0;nt<8;nt++){ cs[nt]=0.f; cq[nt]=0.f; }
    #pragma unroll
    for (int mt=0;mt<2;mt++)
      #pragma unroll
      for (int nt=0;nt<8;nt++)
        #pragma unroll
        for (int r=0;r<4;r++){ float v = acc[mt][nt][r]; cs[nt] += v; cq[nt] = fmaf(v,v,cq[nt]); }
    #pragma unroll
    for (int nt=0;nt<8;nt++){
      cs[nt] += __shfl_xor(cs[nt], 16); cq[nt] += __shfl_xor(cq[nt], 16);
      cs[nt] += __shfl_xor(cs[nt], 32); cq[nt] += __shfl_xor(cq[nt], 32);
    }
    if (lq == 0){
      #pragma unroll
      for (int nt=0;nt<8;nt++){ redS[w][nt*16+lr] = cs[nt]; redQ[w][nt*16+lr] = cq[nt]; }
    }
  }
  __syncthreads();
  if (tid < 128){
    float S = redS[0][tid]+redS[1][tid]+redS[2][tid]+redS[3][tid];
    float Q = redQ[0][tid]+redQ[1][tid]+redQ[2][tid]+redQ[3][tid];
    float m = S*(1.f/128.f);
    float var = Q*(1.f/128.f) - m*m;
    stats[0][tid] = m; stats[1][tid] = rsqrtf(var + 1e-5f);
  }
  __syncthreads();
  #pragma unroll
  for (int mt=0;mt<2;mt++){
    int fo1b = w*32 + mt*16 + lq*4;
    float ga[4], be[4];
    #pragma unroll
    for (int r=0;r<4;r++){ ga[r] = g1v[fo1b+r]; be[r] = bt1v[fo1b+r]; }
    #pragma unroll
    for (int nt=0;nt<8;nt++){
      int col = nt*16 + lr;
      union { __bf16 h[4]; uint2 u; } o;
      #pragma unroll
      for (int r=0;r<4;r++){
        float xx = (acc[mt][nt][r] - stats[0][col]) * stats[1][col] * ga[r] + be[r];
        o.h[r] = (__bf16)fmaxf(xx, 0.f);
      }
      *(uint2*)&y1T[col*128 + (fo1b ^ ((col&15)<<3))] = o.u;
    }
  }
  __syncthreads();

  f32x4 acc2[2][8];
  #pragma unroll
  for (int a=0;a<2;a++)
    #pragma unroll
    for (int b=0;b<8;b++) acc2[a][b] = (f32x4){0.f,0.f,0.f,0.f};
  for (int ks2=0; ks2<4; ks2++){
    if (ks2) __syncthreads();
    { int fo = tid>>1, half = tid&1;
      const uint4* src = (const uint4*)(W2t + (size_t)fo*128 + ks2*32 + half*16);
      uint4 v0 = src[0], v1 = src[1];
      *(uint4*)&Wc[fo*32 + (((half*2+0) ^ (fo&3))<<3)] = v0;
      *(uint4*)&Wc[fo*32 + (((half*2+1) ^ (fo&3))<<3)] = v1;
    }
    __syncthreads();
    bf16x8 af[2], bfr[8];
    #pragma unroll
    for (int mt=0;mt<2;mt++){ int fo = w*32+mt*16+lr; af[mt] = *(const bf16x8*)&Wc[fo*32 + ((lq ^ (fo&3))<<3)]; }
    #pragma unroll
    for (int nt=0;nt<8;nt++){ int cr = nt*16+lr; bfr[nt] = *(const bf16x8*)&y1T[cr*128 + ((ks2*32 + lq*8) ^ ((cr&15)<<3))]; }
    #pragma unroll
    for (int mt=0;mt<2;mt++)
      #pragma unroll
      for (int nt=0;nt<8;nt++)
        acc2[mt][nt] = __builtin_amdgcn_mfma_f32_16x16x32_bf16(af[mt], bfr[nt], acc2[mt][nt], 0,0,0);
  }

  #pragma unroll
  for (int mt=0;mt<2;mt++){
    #pragma unroll
    for (int r=0;r<4;r++){
      float bv = b2v[w*32 + mt*16 + lq*4 + r];
      #pragma unroll
      for (int nt=0;nt<8;nt++) acc2[mt][nt][r] += bv;
    }
  }
  {
    float cs[8], cq[8];
    #pragma unroll
    for (int nt=0;nt<8;nt++){ cs[nt]=0.f; cq[nt]=0.f; }
    #pragma unroll
    for (int mt=0;mt<2;mt++)
      #pragma unroll
      for (int nt=0;nt<8;nt++)
        #pragma unroll
        for (int r=0;r<4;r++){ float v = acc2[mt][nt][r]; cs[nt] += v; cq[nt] = fmaf(v,v,cq[nt]); }
    #pragma unroll
    for (int nt=0;nt<8;nt++){
      cs[nt] += __shfl_xor(cs[nt], 16); cq[nt] += __shfl_xor(cq[nt], 16);
      cs[nt] += __shfl_xor(cs[nt], 32); cq[nt] += __shfl_xor(cq[nt], 32);
    }
    if (lq == 0){
      #pragma unroll
      for (int nt=0;nt<8;nt++){ redS[w][nt*16+lr] = cs[nt]; redQ[w][nt*16+lr] = cq[nt]; }
    }
  }
  __syncthreads();
  if (tid < 128){
    float S = redS[0][tid]+redS[1][tid]+redS[2][tid]+redS[3][tid];
    float Q = redQ[0][tid]+redQ[1][tid]+redQ[2][tid]+redQ[3][tid];
    float m = S*(1.f/128.f);
    float var = Q*(1.f/128.f) - m*m;
    stats[0][tid] = m; stats[1][tid] = rsqrtf(var + 1e-5f);
  }
  __syncthreads();
  #pragma unroll
  for (int mt=0;mt<2;mt++){
    #pragma unroll
    for (int r=0;r<4;r++){
      int fo = w*32 + mt*16 + lq*4 + r;
      float ga = g2v[fo], be = bt2v[fo];
      size_t rowb = ((size_t)(bl*128 + fo)<<12) + colInB;
      #pragma unroll
      for (int nt=0;nt<8;nt++){
        int cp = nt*16 + lr;
        float xx = (acc2[mt][nt][r] - stats[0][cp]) * stats[1][cp] * ga + be;
        float o = fmaxf(xx, 0.f);
        float old = (float)Xold[rowb + cp];
        Xnew[rowb + cp] = (__bf16)(o + old);
      }
    }
  }
}

// ---------------- symmetrize: out = in + in^T (per plane, bf16) ----------------
__global__ __launch_bounds__(256) void k_sym(const __bf16* __restrict__ Xin, __bf16* __restrict__ Xout){
  __shared__ float P[64][65];
  size_t base = (size_t)blockIdx.x * 4096;
  int tid = threadIdx.x;
  int f = tid*16, r = f>>6, c = f&63;
  union { __bf16 h[16]; uint4 u[2]; } in;
  in.u[0] = *(const uint4*)(Xin + base + f);
  in.u[1] = *(const uint4*)(Xin + base + f + 8);
  #pragma unroll
  for (int e=0;e<16;e++) P[r][c+e] = (float)in.h[e];
  __syncthreads();
  union { __bf16 h[16]; uint4 u[2]; } o;
  #pragma unroll
  for (int e=0;e<16;e++) o.h[e] = (__bf16)(P[r][c+e] + P[c+e][r]);
  *(uint4*)(Xout + base + f)     = o.u[0];
  *(uint4*)(Xout + base + f + 8) = o.u[1];
}

// ---------------- to node-major: NM[g*4096+cell][d] = S[g*128+d][cell] ----------------
__global__ __launch_bounds__(256) void k_tonm(const __bf16* __restrict__ S, __bf16* __restrict__ NM){
  __shared__ unsigned short L[64][65];
  int b = blockIdx.x;
  int g = b >> 7, dh = (b>>6)&1, cc = b&63;
  int cell0 = cc*64, d0 = dh*64;
  int tid = threadIdx.x;
  int r = tid>>2, c = (tid&3)*16;
  union { unsigned short h[16]; uint4 u[2]; } in;
  const unsigned short* src = (const unsigned short*)S + ((size_t)(g*128 + d0 + r)<<12) + cell0 + c;
  in.u[0] = *(const uint4*)src;
  in.u[1] = *(const uint4*)(src + 8);
  #pragma unroll
  for (int e=0;e<16;e++) L[r][c+e] = in.h[e];
  __syncthreads();
  union { unsigned short h[16]; uint4 u[2]; } o;
  int cr = tid>>2, dc = (tid&3)*16;
  #pragma unroll
  for (int e=0;e<16;e++) o.h[e] = L[dc+e][cr];
  unsigned short* dst = (unsigned short*)NM + (size_t)(g*4096 + cell0 + cr)*128 + d0 + dc;
  *(uint4*)dst       = o.u[0];
  *(uint4*)(dst + 8) = o.u[1];
}

// ---------------- mlp hidden from cell-major ----------------
__global__ __launch_bounds__(256) void k_mlph(const __bf16* __restrict__ NM,
    const __bf16* __restrict__ Wt, const float* __restrict__ bias, __bf16* __restrict__ hid){
  __shared__ __align__(16) unsigned char WcB[8192];
  __shared__ __align__(16) unsigned char EcB[8192];
  __bf16* Wc = (__bf16*)WcB;
  unsigned char* Ec = EcB;
  int tid = threadIdx.x, w = tid>>6, lane = tid&63, lr = lane&15, lq = lane>>4;
  int g = blockIdx.x >> 5;
  size_t cellbase = ((size_t)g<<12) + ((size_t)(blockIdx.x & 31) << 7);
  int mh = w&1, nh = w>>1;
  f32x4 acc[4][4];
  #pragma unroll
  for (int a=0;a<4;a++)
    #pragma unroll
    for (int b=0;b<4;b++) acc[a][b] = (f32x4){0.f,0.f,0.f,0.f};
  for (int ks=0; ks<4; ks++){
    __syncthreads();
    { int fo = tid>>1, half = tid&1;
      const uint4* src = (const uint4*)(Wt + (size_t)fo*128 + ks*32 + half*16);
      uint4 v0 = src[0], v1 = src[1];
      *(uint4*)&Wc[fo*32 + (((half*2+0) ^ (fo&3))<<3)] = v0;
      *(uint4*)&Wc[fo*32 + (((half*2+1) ^ (fo&3))<<3)] = v1;
    }
    { int cell = tid>>1, half = tid&1;
      const uint4* src = (const uint4*)(NM + (cellbase + cell)*128 + ks*32 + half*16);
      uint4 v0 = src[0], v1 = src[1];
      *(uint4*)(Ec + cell*64 + (((half*2+0) ^ (cell&3))<<4)) = v0;
      *(uint4*)(Ec + cell*64 + (((half*2+1) ^ (cell&3))<<4)) = v1;
    }
    __syncthreads();
    bf16x8 af[4], bfr[4];
    #pragma unroll
    for (int mt=0;mt<4;mt++){ int cr = mh*64 + mt*16 + lr; af[mt] = *(const bf16x8*)(Ec + cr*64 + ((lq ^ (cr&3))<<4)); }
    #pragma unroll
    for (int nt=0;nt<4;nt++){ int fo = nh*64 + nt*16 + lr; bfr[nt] = *(const bf16x8*)&Wc[fo*32 + ((lq ^ (fo&3))<<3)]; }
    #pragma unroll
    for (int mt=0;mt<4;mt++)
      #pragma unroll
      for (int nt=0;nt<4;nt++)
        acc[mt][nt] = __builtin_amdgcn_mfma_f32_16x16x32_bf16(af[mt], bfr[nt], acc[mt][nt], 0,0,0);
  }
  #pragma unroll
  for (int mt=0;mt<4;mt++)
    #pragma unroll
    for (int r=0;r<4;r++){
      size_t cell = cellbase + mh*64 + mt*16 + lq*4 + r;
      #pragma unroll
      for (int nt=0;nt<4;nt++){
        int fo = nh*64 + nt*16 + lr;
        hid[cell*128 + fo] = (__bf16)silu_f(acc[mt][nt][r] + bias[fo]);
      }
    }
}

// ---------------- ym[(g,i)][fo] = mean over v of hid[v*64+i][fo] ----------------
__global__ void k_ymean(const __bf16* __restrict__ hid, float* __restrict__ ym){
  __shared__ float red[256];
  int g = blockIdx.x >> 6, u = blockIdx.x & 63;
  int fo = threadIdx.x & 127, vh = threadIdx.x >> 7;
  const unsigned short* hu = (const unsigned short*)hid;
  float s = 0.f;
  for (int v = vh; v < 64; v += 2)
    s += bf2f(hu[((size_t)g*4096 + v*64 + u)*128 + fo]);
  red[threadIdx.x] = s;
  __syncthreads();
  if (vh == 0) ym[((size_t)g*64 + u)*128 + fo] = (red[fo] + red[128+fo]) * (1.f/64.f);
}

// ---------------- h2 = ym @ mlp_W2 + b2 ----------------
__global__ void k_h2(const float* __restrict__ ym, const float* __restrict__ W2,
                     const float* __restrict__ b2, float* __restrict__ h2){
  int row = blockIdx.x, fo = threadIdx.x;
  __shared__ float rr[128];
  rr[fo] = ym[(size_t)row*128 + fo];
  __syncthreads();
  float a = b2[fo];
  #pragma unroll 4
  for (int k=0;k<128;k++) a = fmaf(rr[k], W2[k*128+fo], a);
  h2[(size_t)row*128+fo] = a;
}

// ---------------- final MLP (MFMA): 64 rows/block; GATHER=1 edge rows, 0 h2 rows ----------------
template<int GATHER>
__global__ __launch_bounds__(256) void k_fmlp(const __bf16* __restrict__ NM, const float* __restrict__ RWS,
    const int* __restrict__ ei,
    const __bf16* __restrict__ W1t, const float* __restrict__ b1,
    const __bf16* __restrict__ W2t, const float* __restrict__ b2,
    float* __restrict__ outp, int b0){
  __shared__ __align__(16) unsigned char RA[32768];   // eo(16K)+Wc(16K) -> hid(32K)
  __shared__ __align__(16) unsigned char RB[8192];    // W2 slices
  __shared__ int cells[64];
  __bf16* eo  = (__bf16*)RA;           // [64 rows][128 k] swizzled
  __bf16* Wc  = (__bf16*)(RA + 16384); // [256 fo][32 k] swizzled
  __bf16* hid = (__bf16*)RA;           // [64 rows][256 fo] swizzled
  __bf16* W2c = (__bf16*)RB;           // [128 fo2][32 k] swizzled
  int tid = threadIdx.x, w = tid>>6, lane = tid&63, lr = lane&15, lq = lane>>4;
  int r0 = blockIdx.x*64;
  if (GATHER){
    if (tid < 64){
      int e = b0*512 + r0 + tid;
      int s = ei[e], dN = ei[EDGES+e];
      cells[tid] = ((s>>6) - b0)*4096 + (dN&63)*64 + (s&63);
    }
    __syncthreads();
  }
  { // stage eo
    int el = tid>>2, o4 = tid&3;
    if (GATHER){
      const unsigned short* src = (const unsigned short*)NM + (size_t)cells[el]*128;
      #pragma unroll
      for (int j=0;j<4;j++){
        int ch = o4*4 + j;
        uint4 v = *(const uint4*)(src + ch*8);
        *(uint4*)&eo[el*128 + ((ch*8) ^ ((el&15)*8))] = v;
      }
    } else {
      const float* src = RWS + (size_t)(r0 + el)*128;
      #pragma unroll
      for (int j=0;j<4;j++){
        int ch = o4*4 + j;
        union { __bf16 h[8]; uint4 u; } pk;
        #pragma unroll
        for (int e2=0;e2<8;e2++) pk.h[e2] = (__bf16)src[ch*8 + e2];
        *(uint4*)&eo[el*128 + ((ch*8) ^ ((el&15)*8))] = pk.u;
      }
    }
  }
  // GEMM1: M=256 fo (wave owns fo block w*64), N=64 rows, K=128
  f32x4 acc[4][4];
  #pragma unroll
  for (int a=0;a<4;a++)
    #pragma unroll
    for (int b=0;b<4;b++) acc[a][b] = (f32x4){0.f,0.f,0.f,0.f};
  for (int ks=0; ks<4; ks++){
    if (ks) __syncthreads();
    { int fo = tid;
      const uint4* src = (const uint4*)(W1t + (size_t)fo*128 + ks*32);
      #pragma unroll
      for (int o=0;o<4;o++){
        uint4 v = src[o];
        *(uint4*)&Wc[fo*32 + ((o ^ (fo&3))<<3)] = v;
      }
    }
    __syncthreads();
    bf16x8 af[4], bfr[4];
    #pragma unroll
    for (int mt=0;mt<4;mt++){ int fo = w*64+mt*16+lr; af[mt] = *(const bf16x8*)&Wc[fo*32 + ((lq ^ (fo&3))<<3)]; }
    #pragma unroll
    for (int nt=0;nt<4;nt++){ int ed = nt*16+lr; bfr[nt] = *(const bf16x8*)&eo[ed*128 + ((ks*32+lq*8) ^ ((ed&15)*8))]; }
    #pragma unroll
    for (int mt=0;mt<4;mt++)
      #pragma unroll
      for (int nt=0;nt<4;nt++)
        acc[mt][nt] = __builtin_amdgcn_mfma_f32_16x16x32_bf16(af[mt], bfr[nt], acc[mt][nt], 0,0,0);
  }
  __syncthreads();
  // bias1 + relu -> hid (overlays RA)
  #pragma unroll
  for (int mt=0;mt<4;mt++){
    int fob = w*64 + mt*16 + lq*4;
    float bv[4];
    #pragma unroll
    for (int r=0;r<4;r++) bv[r] = b1[fob+r];
    #pragma unroll
    for (int nt=0;nt<4;nt++){
      int ed = nt*16 + lr;
      union { __bf16 h[4]; uint2 u; } o;
      #pragma unroll
      for (int r=0;r<4;r++) o.h[r] = (__bf16)fmaxf(acc[mt][nt][r] + bv[r], 0.f);
      *(uint2*)&hid[ed*256 + (fob ^ ((ed&31)*8))] = o.u;
    }
  }
  // GEMM2: M=128 fo2 (mh*64), N=64 rows (nh*32), K=256
  f32x4 acc2[4][2];
  #pragma unroll
  for (int a=0;a<4;a++)
    #pragma unroll
    for (int b=0;b<2;b++) acc2[a][b] = (f32x4){0.f,0.f,0.f,0.f};
  int mh = w&1, nh = w>>1;
  for (int ks2=0; ks2<8; ks2++){
    __syncthreads();
    { int fo = tid>>1, half = tid&1;
      const uint4* src = (const uint4*)(W2t + (size_t)fo*256 + ks2*32 + half*16);
      uint4 v0 = src[0], v1 = src[1];
      *(uint4*)&W2c[fo*32 + (((half*2+0) ^ (fo&3))<<3)] = v0;
      *(uint4*)&W2c[fo*32 + (((half*2+1) ^ (fo&3))<<3)] = v1;
    }
    __syncthreads();
    bf16x8 af2[4], bfr2[2];
    #pragma unroll
    for (int mt=0;mt<4;mt++){ int fo2 = mh*64+mt*16+lr; af2[mt] = *(const bf16x8*)&W2c[fo2*32 + ((lq ^ (fo2&3))<<3)]; }
    #pragma unroll
    for (int nt=0;nt<2;nt++){ int ed = nh*32+nt*16+lr; bfr2[nt] = *(const bf16x8*)&hid[ed*256 + ((ks2*32+lq*8) ^ ((ed&31)*8))]; }
    #pragma unroll
    for (int mt=0;mt<4;mt++)
      #pragma unroll
      for (int nt=0;nt<2;nt++)
        acc2[mt][nt] = __builtin_amdgcn_mfma_f32_16x16x32_bf16(af2[mt], bfr2[nt], acc2[mt][nt], 0,0,0);
  }
  // bias2 + store (float4 per lane)
  #pragma unroll
  for (int mt=0;mt<4;mt++){
    int fo2b = mh*64 + mt*16 + lq*4;
    float bv[4];
    #pragma unroll
    for (int r=0;r<4;r++) bv[r] = b2[fo2b+r];
    #pragma unroll
    for (int nt=0;nt<2;nt++){
      int ed = nh*32 + nt*16 + lr;
      float4 o = make_float4(acc2[mt][nt][0]+bv[0], acc2[mt][nt][1]+bv[1],
                             acc2[mt][nt][2]+bv[2], acc2[mt][nt][3]+bv[3]);
      *(float4*)(outp + (size_t)(r0 + ed)*128 + fo2b) = o;
    }
  }
}

// ---------------- graph_attr ----------------
__global__ void k_graph(const float* __restrict__ node_out, float* __restrict__ gout){
  int b = blockIdx.x, d = threadIdx.x;
  float s = 0.f;
  for (int i=0;i<64;i++) s += node_out[(size_t)(b*64+i)*128 + d];
  gout[b*128 + d] = s * (1.f/64.f);
}

extern "C" void kernel_launch(void* const* d_in, const int* in_sizes, int n_in,
                              void* d_out, int out_size, void* d_ws, size_t ws_size,
                              hipStream_t stream) {
  const int*   edge_index = (const int*)d_in[1];
  const int*   edge_attr  = (const int*)d_in[2];
  const float* t        = (const float*)d_in[3];
  const float* edge_emb = (const float*)d_in[5];
  const float* temb_W1  = (const float*)d_in[6];
  const float* temb_b1  = (const float*)d_in[7];
  const float* temb_W2  = (const float*)d_in[8];
  const float* temb_b2  = (const float*)d_in[9];
  const float* ein_W1   = (const float*)d_in[14];
  const float* ein_b1   = (const float*)d_in[15];
  const float* ein_W2   = (const float*)d_in[16];
  const float* ein_b2   = (const float*)d_in[17];
  const float* conv_W1  = (const float*)d_in[18];
  const float* conv_b1  = (const float*)d_in[19];
  const float* conv_g1  = (const float*)d_in[20];
  const float* conv_bt1 = (const float*)d_in[21];
  const float* conv_W2  = (const float*)d_in[22];
  const float* conv_b2  = (const float*)d_in[23];
  const float* conv_g2  = (const float*)d_in[24];
  const float* conv_bt2 = (const float*)d_in[25];
  const float* mlp_W1   = (const float*)d_in[26];
  const float* mlp_b1   = (const float*)d_in[27];
  const float* mlp_W2   = (const float*)d_in[28];
  const float* mlp_b2   = (const float*)d_in[29];
  const float* fn_W1    = (const float*)d_in[30];
  const float* fn_b1    = (const float*)d_in[31];
  const float* fn_W2    = (const float*)d_in[32];
  const float* fn_b2    = (const float*)d_in[33];

  float* ws  = (float*)d_ws;
  float* tt  = ws;                      // 4096
  float* enc = ws + 4096;               // 2048
  float* ym  = ws + 6144;               // 262144
  float* h2  = ws + 268288;             // 262144
  __bf16* WT = (__bf16*)(ws + 530432);  // 475136 bf16
  unsigned int* cnt = (unsigned int*)(ws + 768000);  // 2097152 u32
  const size_t HDRF = 2883584;

  __bf16* fnW1t = WT + 409600;          // [256][128]
  __bf16* fnW2t = WT + 442368;          // [128][256]

  size_t availF = ws_size / sizeof(float);
  const int cands[6] = {32, 16, 8, 4, 2, 1};
  int C = 1;
  for (int i = 0; i < 6; i++){
    if (HDRF + 4ull * (size_t)cands[i] * 262144ull <= availF){ C = cands[i]; break; }
  }
  const size_t PCB = (size_t)C * 262144;
  __bf16* A_S = (__bf16*)(ws + HDRF);
  __bf16* X_S = (__bf16*)(ws + HDRF + PCB);
  __bf16* X1  = (__bf16*)(ws + HDRF + 2*PCB);
  __bf16* X2  = (__bf16*)(ws + HDRF + 3*PCB);
  float* outf = (float*)d_out;

  k_temb<<<NB, DD, 0, stream>>>(t, temb_W1, temb_b1, temb_W2, temb_b2, tt);
  k_edgeenc<<<16, 256, 0, stream>>>(edge_emb, ein_W1, ein_b1, ein_W2, ein_b2, enc);
  k_wprep<<<13, 256, 0, stream>>>(conv_W1, conv_W2, mlp_W1, WT);
  k_wprepfn<<<16, 256, 0, stream>>>(fn_W1, fn_W2, fnW1t, fnW2t);

  for (int b0 = 0; b0 < NB; b0 += C){
    hipMemsetAsync(cnt, 0, (size_t)C*4096*16*sizeof(unsigned int), stream);
    k_cnt<<<C*2, 256, 0, stream>>>(edge_index, edge_attr, cnt, b0);
    k_expand<<<C*16, 256, 0, stream>>>(cnt, enc, tt, A_S, b0);

    for (int l=0; l<LAYERS; l++){
      const __bf16* Xs_l = (l==0) ? A_S : X_S;
      k_einsum<<<C*64, 256, 0, stream>>>(A_S, Xs_l, X1, X2);
      k_layer<<<C*32, 256, 0, stream>>>(Xs_l, X1, X2,
          WT + (size_t)l*49152, WT + 294912 + (size_t)l*16384,
          conv_b1 + l*DD, conv_g1 + l*DD, conv_bt1 + l*DD,
          conv_b2 + l*DD, conv_g2 + l*DD, conv_bt2 + l*DD, X_S);
    }

    k_sym<<<C*128, 256, 0, stream>>>(X_S, X2);
    k_tonm<<<C*128, 256, 0, stream>>>(X2, X1);           // X1 = cell-major X
    k_mlph<<<C*32, 256, 0, stream>>>(X1, WT + 393216, mlp_b1, X2);  // X2 = hid cell-major
    k_ymean<<<C*64, 256, 0, stream>>>(X2, ym);
    k_h2<<<C*64, 128, 0, stream>>>(ym, mlp_W2, mlp_b2, h2);
    k_fmlp<1><<<C*8, 256, 0, stream>>>(X1, nullptr, edge_index, fnW1t, fn_b1, fnW2t, fn_b2,
                                       outf + 262144 + (size_t)b0*512*128, b0);
    k_fmlp<0><<<C, 256, 0, stream>>>(nullptr, h2, nullptr, fnW1t, fn_b1, fnW2t, fn_b2,
                                     outf + (size_t)b0*64*128, b0);
    k_graph<<<C, DD, 0, stream>>>(outf + (size_t)b0*64*DD, outf + 2359296 + b0*DD);
  }
}